// Round 1
// baseline (1045.518 us; speedup 1.0000x reference)
//
// R1: full algorithmic rewrite of LowRankModl CG-MRI solve.
//  - tilde-domain (D-twiddle) removes all fft/ifft shifts
//  - per-k-point 3x3 Hermitian kernel W collapses the t dimension:
//    FFT count 3120 -> 780 (256-pt 2D c64)
//  - hand radix-4 DIF FFT, 64 lanes/FFT, LDS exchange, natural-order I/O
//  - fused col-ifft + W-mix + col-fft (in-place); fused row-fft + conj(S)
//    coil-combine + lambda*p + vdot(p,Ap) reduction
//  - CG scalars on device (f64 atomics), exact done-freeze semantics
// ws usage: ~56.6 MB.
#include <hip/hip_runtime.h>
#include <math.h>

#define HW 65536
#define LAM 0.05f

struct Scal {
  double pap_re, pap_im, rs_acc, rs_old;
  int done, pad;
};

__device__ __forceinline__ float2 cadd(float2 a, float2 b){ return make_float2(a.x+b.x, a.y+b.y); }
__device__ __forceinline__ float2 csub(float2 a, float2 b){ return make_float2(a.x-b.x, a.y-b.y); }
__device__ __forceinline__ float2 cmul(float2 a, float2 b){
  return make_float2(a.x*b.x - a.y*b.y, a.x*b.y + a.y*b.x);
}
__device__ __forceinline__ float2 cmulj(float2 a, float2 b){ // conj(a)*b
  return make_float2(a.x*b.x + a.y*b.y, a.x*b.y - a.y*b.x);
}
__device__ __forceinline__ int rev4(int p){
  return ((p&3)<<6) | (((p>>2)&3)<<4) | (((p>>4)&3)<<2) | ((p>>6)&3);
}

// 256-pt FFT, radix-4 DIF, 64 lanes cooperate. element p at lds[base+p*stride].
// SIGN=-1 fwd, +1 inv (unnormalized). Natural-order in AND out (last stage
// writes digit-reversed). Caller must __syncthreads() after filling LDS.
// Ends with __syncthreads().
template<int SIGN>
__device__ void wave_fft256(float2* lds, int base, int stride, int lane){
#pragma unroll
  for (int st=0; st<4; ++st){
    const int B = 256 >> (2*st);
    const int Q = B >> 2;
    int m   = lane & (Q-1);
    int blk = lane >> (6 - 2*st);
    int p0  = blk*B + m;
    float2 x0 = lds[base + (p0      )*stride];
    float2 x1 = lds[base + (p0 +   Q)*stride];
    float2 x2 = lds[base + (p0 + 2*Q)*stride];
    float2 x3 = lds[base + (p0 + 3*Q)*stride];
    float2 a  = cadd(x0,x2), bm = csub(x0,x2);
    float2 c  = cadd(x1,x3), d  = csub(x1,x3);
    float2 jd = make_float2(-(float)SIGN*d.y, (float)SIGN*d.x);
    float2 y0 = cadd(a,c);
    float2 y2 = csub(a,c);
    float2 y1 = cadd(bm,jd);
    float2 y3 = csub(bm,jd);
    if (st < 3){
      float ang = (float)SIGN * 6.28318530717958647f * (float)m / (float)B;
      float s1, c1;
      __sincosf(ang, &s1, &c1);
      float2 w1 = make_float2(c1, s1);
      float2 w2 = make_float2(c1*c1 - s1*s1, 2.f*c1*s1);
      float2 w3 = cmul(w1, w2);
      y1 = cmul(y1, w1); y2 = cmul(y2, w2); y3 = cmul(y3, w3);
      lds[base + (p0      )*stride] = y0;
      lds[base + (p0 +   Q)*stride] = y1;
      lds[base + (p0 + 2*Q)*stride] = y2;
      lds[base + (p0 + 3*Q)*stride] = y3;
      __syncthreads();
    } else {
      // in-place pos would be 4*lane+q; redirect to rev4 -> natural order.
      lds[base + rev4(4*lane+0)*stride] = y0;
      lds[base + rev4(4*lane+1)*stride] = y1;
      lds[base + rev4(4*lane+2)*stride] = y2;
      lds[base + rev4(4*lane+3)*stride] = y3;
      __syncthreads();
    }
  }
}

__global__ void k_scal_init(Scal* sc){
  sc->pap_re = 0.0; sc->pap_im = 0.0; sc->rs_acc = 0.0; sc->rs_old = 0.0;
  sc->done = 0;
}

// W[b][k=s*3+s'][v][u] = (1/65536) * sum_t conj(L_ts) L_ts' mask[b,t,u,v]
__global__ __launch_bounds__(256) void k_w(const float* __restrict__ mask,
                                           const float* __restrict__ tbr,
                                           const float* __restrict__ tbi,
                                           float2* __restrict__ Wb){
  __shared__ float2 wt[9][16][17];
  int tid = threadIdx.x;
  int bx = blockIdx.x;       // 0..255 (16x16 tiles)
  int b  = blockIdx.y;
  int u0 = (bx>>4)<<4, v0 = (bx&15)<<4;
  int u_l = tid>>4, v_l = tid&15;
  int pix = (u0+u_l)*256 + (v0+v_l);
  float d0=0,d1=0,d2=0, o01r=0,o01i=0, o02r=0,o02i=0, o12r=0,o12i=0;
#pragma unroll
  for (int t=0;t<12;t++){
    float m = mask[(size_t)(b*12+t)*HW + pix];
    int lb = (b*12+t)*3;
    float l0r = tbr[lb+0], l0i = tbi[lb+0];
    float l1r = tbr[lb+1], l1i = tbi[lb+1];
    float l2r = tbr[lb+2], l2i = tbi[lb+2];
    d0 += m*(l0r*l0r + l0i*l0i);
    d1 += m*(l1r*l1r + l1i*l1i);
    d2 += m*(l2r*l2r + l2i*l2i);
    o01r += m*(l0r*l1r + l0i*l1i); o01i += m*(l0r*l1i - l0i*l1r);
    o02r += m*(l0r*l2r + l0i*l2i); o02i += m*(l0r*l2i - l0i*l2r);
    o12r += m*(l1r*l2r + l1i*l2i); o12i += m*(l1r*l2i - l1i*l2r);
  }
  const float s = 1.0f/65536.0f;
  wt[0][u_l][v_l] = make_float2(d0*s, 0.f);
  wt[1][u_l][v_l] = make_float2(o01r*s,  o01i*s);
  wt[2][u_l][v_l] = make_float2(o02r*s,  o02i*s);
  wt[3][u_l][v_l] = make_float2(o01r*s, -o01i*s);
  wt[4][u_l][v_l] = make_float2(d1*s, 0.f);
  wt[5][u_l][v_l] = make_float2(o12r*s,  o12i*s);
  wt[6][u_l][v_l] = make_float2(o02r*s, -o02i*s);
  wt[7][u_l][v_l] = make_float2(o12r*s, -o12i*s);
  wt[8][u_l][v_l] = make_float2(d2*s, 0.f);
  __syncthreads();
  int u_l2 = tid&15, v_l2 = tid>>4;
#pragma unroll
  for (int k=0;k<9;k++){
    Wb[ ((size_t)(b*9+k)*256 + (v0+v_l2))*256 + (u0+u_l2) ] = wt[k][u_l2][v_l2];
  }
}

// bufA[(b*10+c)*3+s] = (1/256) * D * sum_t conj(L_ts) * Y[b,t,c]
__global__ __launch_bounds__(256) void k_yhat(const float* __restrict__ kr,
                                              const float* __restrict__ ki,
                                              const float* __restrict__ tbr,
                                              const float* __restrict__ tbi,
                                              float2* __restrict__ bufA){
  int tid = threadIdx.x;
  int pix = blockIdx.x*256 + tid;
  int c = blockIdx.y, b = blockIdx.z;
  float a0r=0,a0i=0,a1r=0,a1i=0,a2r=0,a2i=0;
#pragma unroll
  for (int t=0;t<12;t++){
    size_t off = ((size_t)((b*12+t)*10+c))*HW + pix;
    float yr = kr[off], yi = ki[off];
    int lb = (b*12+t)*3;
    float l0r = tbr[lb+0], l0i = tbi[lb+0];
    float l1r = tbr[lb+1], l1i = tbi[lb+1];
    float l2r = tbr[lb+2], l2i = tbi[lb+2];
    a0r += l0r*yr + l0i*yi;  a0i += l0r*yi - l0i*yr;
    a1r += l1r*yr + l1i*yi;  a1i += l1r*yi - l1i*yr;
    a2r += l2r*yr + l2i*yi;  a2i += l2r*yi - l2i*yr;
  }
  float sgn = (((pix>>8) ^ pix) & 1) ? -1.f : 1.f;
  float s = sgn * (1.0f/256.0f);
  size_t base = ((size_t)(b*10+c))*3*HW + pix;
  bufA[base + 0*(size_t)HW] = make_float2(a0r*s, a0i*s);
  bufA[base + 1*(size_t)HW] = make_float2(a1r*s, a1i*s);
  bufA[base + 2*(size_t)HW] = make_float2(a2r*s, a2i*s);
}

// bvec = lambda * D * MO
__global__ __launch_bounds__(256) void k_bvec0(const float* __restrict__ mor,
                                               const float* __restrict__ moi,
                                               float2* __restrict__ bvec){
  int i = blockIdx.x*256 + threadIdx.x;   // 0..393215
  int pix = i & (HW-1);
  float sgn = (((pix>>8)^pix)&1) ? -1.f : 1.f;
  float s = sgn*LAM;
  bvec[i] = make_float2(s*mor[i], s*moi[i]);
}

// Column pass over bufA, in-place. MODE 0: col-fft (sign -1) only (setup).
// MODE 1: col-ifft (+1), 3x3 W mix, col-fft (-1).
template<int MODE>
__global__ __launch_bounds__(256) void k_colpass(float2* __restrict__ bufA,
                                                 const float2* __restrict__ Wb){
  __shared__ float2 tile[3*2304];   // [s][u][col], col stride pad 9
  int tid = threadIdx.x;
  int j0 = blockIdx.x*8;
  int c = blockIdx.y, b = blockIdx.z;
  // load
  for (int s=0;s<3;s++){
    const float2* src = bufA + ((size_t)((b*10+c)*3+s))*HW;
#pragma unroll
    for (int it=0; it<8; it++){
      int idx = it*256 + tid;
      int u = idx>>3, col = idx&7;
      tile[s*2304 + u*9 + col] = src[u*256 + j0 + col];
    }
  }
  __syncthreads();
  int wave = tid>>6, lane = tid&63;
  if (MODE==0){
    for (int s=0;s<3;s++)
      for (int cc=0;cc<2;cc++)
        wave_fft256<-1>(tile, s*2304 + wave*2 + cc, 9, lane);
  } else {
    for (int s=0;s<3;s++)
      for (int cc=0;cc<2;cc++)
        wave_fft256<1>(tile, s*2304 + wave*2 + cc, 9, lane);
    // W mix (pointwise over (u, col)); fft left natural order + synced.
    const float2* Wp = Wb + (size_t)b*9*HW;
#pragma unroll
    for (int it=0; it<8; it++){
      int col = tid>>5;             // 0..7
      int u   = it*32 + (tid&31);   // coalesced in u for W reads
      int v   = j0 + col;
      float2 x0 = tile[0*2304 + u*9 + col];
      float2 x1 = tile[1*2304 + u*9 + col];
      float2 x2 = tile[2*2304 + u*9 + col];
      size_t wb = ((size_t)v)*256 + u;
      float2 y0 = cmul(Wp[(size_t)(0*256)*256 + wb], x0);
      y0 = cadd(y0, cmul(Wp[(size_t)(1*256)*256 + wb], x1));
      y0 = cadd(y0, cmul(Wp[(size_t)(2*256)*256 + wb], x2));
      float2 y1 = cmul(Wp[(size_t)(3*256)*256 + wb], x0);
      y1 = cadd(y1, cmul(Wp[(size_t)(4*256)*256 + wb], x1));
      y1 = cadd(y1, cmul(Wp[(size_t)(5*256)*256 + wb], x2));
      float2 y2 = cmul(Wp[(size_t)(6*256)*256 + wb], x0);
      y2 = cadd(y2, cmul(Wp[(size_t)(7*256)*256 + wb], x1));
      y2 = cadd(y2, cmul(Wp[(size_t)(8*256)*256 + wb], x2));
      tile[0*2304 + u*9 + col] = y0;
      tile[1*2304 + u*9 + col] = y1;
      tile[2*2304 + u*9 + col] = y2;
    }
    __syncthreads();
    for (int s=0;s<3;s++)
      for (int cc=0;cc<2;cc++)
        wave_fft256<-1>(tile, s*2304 + wave*2 + cc, 9, lane);
  }
  // store
  for (int s=0;s<3;s++){
    float2* dst = bufA + ((size_t)((b*10+c)*3+s))*HW;
#pragma unroll
    for (int it=0; it<8; it++){
      int idx = it*256 + tid;
      int u = idx>>3, col = idx&7;
      dst[u*256 + j0 + col] = tile[s*2304 + u*9 + col];
    }
  }
}

// Row pass for iteration: bufA[(b,c,s)] rows = row-ifft(S_c * p_s)
__global__ __launch_bounds__(256) void k_rowifft(const float2* __restrict__ p,
                                                 const float* __restrict__ sr_,
                                                 const float* __restrict__ si_,
                                                 float2* __restrict__ bufA){
  __shared__ float2 tile[4*256];
  int tid = threadIdx.x;
  int bx = blockIdx.x;            // 0..63 (4 rows each)
  int cs = blockIdx.y;            // 0..29
  int b  = blockIdx.z;
  int c = cs/3, s = cs%3;
  const float2* pp = p + (size_t)(b*3+s)*HW;
  const float* sr = sr_ + (size_t)(b*10+c)*HW;
  const float* si = si_ + (size_t)(b*10+c)*HW;
#pragma unroll
  for (int j=0;j<4;j++){
    int row = bx*4+j;
    float2 pv = pp[row*256+tid];
    float2 sv = make_float2(sr[row*256+tid], si[row*256+tid]);
    tile[j*256+tid] = cmul(sv, pv);
  }
  __syncthreads();
  int wave = tid>>6, lane = tid&63;
  wave_fft256<1>(tile, wave*256, 1, lane);
  float2* dst = bufA + (size_t)((b*10+c)*3+s)*HW;
#pragma unroll
  for (int j=0;j<4;j++){
    dst[(bx*4+j)*256+tid] = tile[j*256+tid];
  }
}

// Row-fft + conj(S) coil combine + addend + dot reduction.
// SETUP=1: out=bvec (addend=bvec, ascale=1), accumulates sum|out|^2 -> rs_acc
// SETUP=0: out=Ap (addend=p, ascale=lam), accumulates conj(p).Ap -> pap
template<int SETUP>
__global__ __launch_bounds__(64) void k3_rowfft(const float2* __restrict__ bufA,
                                                const float* __restrict__ sr_,
                                                const float* __restrict__ si_,
                                                const float2* __restrict__ addend,
                                                float ascale,
                                                float2* __restrict__ out,
                                                const float2* __restrict__ dotleft,
                                                Scal* sc){
  __shared__ float2 tile[256];
  int lane = threadIdx.x;
  int r = blockIdx.x, s = blockIdx.y, b = blockIdx.z;
  if (!SETUP && r==0 && s==0 && b==0 && lane==0) sc->rs_acc = 0.0;
  float2 acc[4];
#pragma unroll
  for (int q=0;q<4;q++) acc[q] = make_float2(0.f,0.f);
  for (int c=0;c<10;c++){
    const float2* src = bufA + (size_t)((b*10+c)*3+s)*HW + (size_t)r*256;
    __syncthreads();
#pragma unroll
    for (int q=0;q<4;q++) tile[lane+64*q] = src[lane+64*q];
    __syncthreads();
    wave_fft256<-1>(tile, 0, 1, lane);
    const float* sr = sr_ + (size_t)(b*10+c)*HW + (size_t)r*256;
    const float* si = si_ + (size_t)(b*10+c)*HW + (size_t)r*256;
#pragma unroll
    for (int q=0;q<4;q++){
      int k = lane+64*q;
      float2 sv = make_float2(sr[k], si[k]);
      acc[q] = cadd(acc[q], cmulj(sv, tile[k]));
    }
  }
  const float2* ad = addend + (size_t)(b*3+s)*HW + (size_t)r*256;
  float2* op = out + (size_t)(b*3+s)*HW + (size_t)r*256;
  double dre=0.0, dim=0.0;
#pragma unroll
  for (int q=0;q<4;q++){
    int k = lane+64*q;
    float2 a = acc[q];
    float2 av = ad[k];
    a.x += ascale*av.x; a.y += ascale*av.y;
    op[k] = a;
    if (SETUP){
      dre += (double)a.x*a.x + (double)a.y*a.y;
    } else {
      float2 pl = dotleft[(size_t)(b*3+s)*HW + (size_t)r*256 + k];
      dre += (double)pl.x*a.x + (double)pl.y*a.y;
      dim += (double)pl.x*a.y - (double)pl.y*a.x;
    }
  }
  for (int off=32; off>0; off>>=1){
    dre += __shfl_down(dre, off, 64);
    if (!SETUP) dim += __shfl_down(dim, off, 64);
  }
  if (lane==0){
    if (SETUP) atomicAdd(&sc->rs_acc, dre);
    else { atomicAdd(&sc->pap_re, dre); atomicAdd(&sc->pap_im, dim); }
  }
}

__global__ __launch_bounds__(256) void k_cginit(const float2* __restrict__ bvec,
                                                float2* __restrict__ z,
                                                float2* __restrict__ r,
                                                float2* __restrict__ p,
                                                Scal* sc){
  int i = blockIdx.x*256 + threadIdx.x;
  float2 bv = bvec[i];
  z[i] = make_float2(0.f,0.f);
  r[i] = bv; p[i] = bv;
  if (i==0){ sc->rs_old = sc->rs_acc; sc->pap_re=0.0; sc->pap_im=0.0; }
}

__global__ __launch_bounds__(256) void k_upzr(float2* __restrict__ z,
                                              float2* __restrict__ r,
                                              const float2* __restrict__ p,
                                              const float2* __restrict__ Ap,
                                              Scal* sc){
  __shared__ double sd[4];
  int tid = threadIdx.x;
  int i = blockIdx.x*256 + tid;
  int done = sc->done;
  double local = 0.0;
  if (!done){
    double dre = sc->pap_re + 1e-20, dim = sc->pap_im;
    double den = dre*dre + dim*dim;
    double rs = sc->rs_old;
    float2 alpha = make_float2((float)( rs*dre/den), (float)(-rs*dim/den));
    float2 pv = p[i], apv = Ap[i];
    float2 zv = cadd(z[i], cmul(alpha, pv));
    float2 rv = csub(r[i], cmul(alpha, apv));
    z[i] = zv; r[i] = rv;
    local = (double)rv.x*rv.x + (double)rv.y*rv.y;
  }
  for (int off=32; off>0; off>>=1) local += __shfl_down(local, off, 64);
  if ((tid&63)==0) sd[tid>>6] = local;
  __syncthreads();
  if (tid==0 && !done){
    atomicAdd(&sc->rs_acc, sd[0]+sd[1]+sd[2]+sd[3]);
  }
}

__global__ __launch_bounds__(256) void k_upp(float2* __restrict__ p,
                                             const float2* __restrict__ r,
                                             Scal* sc){
  if (sc->done) return;
  int i = blockIdx.x*256 + threadIdx.x;
  float beta = (float)(sc->rs_acc / (sc->rs_old + 1e-20));
  float2 pv = p[i];
  p[i] = make_float2(r[i].x + beta*pv.x, r[i].y + beta*pv.y);
}

__global__ void k_beta(Scal* sc){
  if (!sc->done){
    sc->rs_old = sc->rs_acc;
    if (fabs(sc->rs_old) < 1e-10) sc->done = 1;
  }
  sc->pap_re = 0.0; sc->pap_im = 0.0;
}

__global__ __launch_bounds__(256) void k_out(const float2* __restrict__ z,
                                             float* __restrict__ out){
  int i = blockIdx.x*256 + threadIdx.x;
  int pix = i & (HW-1);
  float sgn = (((pix>>8)^pix)&1) ? -1.f : 1.f;
  float2 zv = z[i];
  out[2*i]   = sgn*zv.x;
  out[2*i+1] = sgn*zv.y;
}

extern "C" void kernel_launch(void* const* d_in, const int* in_sizes, int n_in,
                              void* d_out, int out_size, void* d_ws, size_t ws_size,
                              hipStream_t stream){
  const float* kr   = (const float*)d_in[0];
  const float* ki   = (const float*)d_in[1];
  const float* mor  = (const float*)d_in[2];
  const float* moi  = (const float*)d_in[3];
  const float* sr   = (const float*)d_in[4];
  const float* si   = (const float*)d_in[5];
  const float* tbr  = (const float*)d_in[6];
  const float* tbi  = (const float*)d_in[7];
  const float* mask = (const float*)d_in[8];
  float* out = (float*)d_out;

  float2* ws   = (float2*)d_ws;
  float2* bufA = ws;                 // 60*HW = 3,932,160 float2
  float2* Wb   = ws + 3932160;       // 2*9*HW = 1,179,648
  float2* bvec = ws + 5111808;       // 393,216 each below
  float2* z    = ws + 5505024;
  float2* r    = ws + 5898240;
  float2* p    = ws + 6291456;
  float2* Ap   = ws + 6684672;
  Scal*   sc   = (Scal*)(ws + 7077888);

  k_scal_init<<<dim3(1),dim3(1),0,stream>>>(sc);
  k_w<<<dim3(256,2),dim3(256),0,stream>>>(mask, tbr, tbi, Wb);
  k_yhat<<<dim3(256,10,2),dim3(256),0,stream>>>(kr, ki, tbr, tbi, bufA);
  k_bvec0<<<dim3(1536),dim3(256),0,stream>>>(mor, moi, bvec);
  k_colpass<0><<<dim3(32,10,2),dim3(256),0,stream>>>(bufA, Wb);
  k3_rowfft<1><<<dim3(256,3,2),dim3(64),0,stream>>>(bufA, sr, si, bvec, 1.0f,
                                                    bvec, (const float2*)0, sc);
  k_cginit<<<dim3(1536),dim3(256),0,stream>>>(bvec, z, r, p, sc);
  for (int it=0; it<6; ++it){
    k_rowifft<<<dim3(64,30,2),dim3(256),0,stream>>>(p, sr, si, bufA);
    k_colpass<1><<<dim3(32,10,2),dim3(256),0,stream>>>(bufA, Wb);
    k3_rowfft<0><<<dim3(256,3,2),dim3(64),0,stream>>>(bufA, sr, si, p, LAM,
                                                      Ap, p, sc);
    k_upzr<<<dim3(1536),dim3(256),0,stream>>>(z, r, p, Ap, sc);
    k_upp<<<dim3(1536),dim3(256),0,stream>>>(p, r, sc);
    k_beta<<<dim3(1),dim3(1),0,stream>>>(sc);
  }
  k_out<<<dim3(1536),dim3(256),0,stream>>>(z, out);
}

// Round 3
// 1043.202 us; speedup vs baseline: 1.0022x; 1.0022x over previous
//
// R3: R2 with the k_combine grid bug fixed (3072 -> 1536 blocks; index
// space is 6*HW = 393216). R2's OOB read past the workspace caused the
// HSA abort.
//  - wave-synchronous 256-pt FFT (wave-private LDS + lgkmcnt sync, no
//    __syncthreads inside FFT); XOR swizzle u^(u>>4) for uniform banks
//  - k3_rowfft (64-thr latency trap) split into 256-thr in-place row-FFT
//    + elementwise combine/reduce kernel
//  - colpass: 4 cols/block (24KB LDS), 2 block barriers total
#include <hip/hip_runtime.h>
#include <math.h>

#define HW 65536
#define LAM 0.05f

struct Scal {
  double pap_re, pap_im, rs_acc, rs_old;
  int done, pad;
};

__device__ __forceinline__ float2 cadd(float2 a, float2 b){ return make_float2(a.x+b.x, a.y+b.y); }
__device__ __forceinline__ float2 csub(float2 a, float2 b){ return make_float2(a.x-b.x, a.y-b.y); }
__device__ __forceinline__ float2 cmul(float2 a, float2 b){
  return make_float2(a.x*b.x - a.y*b.y, a.x*b.y + a.y*b.x);
}
__device__ __forceinline__ float2 cmulj(float2 a, float2 b){ // conj(a)*b
  return make_float2(a.x*b.x + a.y*b.y, a.x*b.y - a.y*b.x);
}
__device__ __forceinline__ int rev4(int p){
  return ((p&3)<<6) | (((p>>2)&3)<<4) | (((p>>4)&3)<<2) | ((p>>6)&3);
}
__device__ __forceinline__ int swz(int p){ return p ^ (p>>4); }

// wave-local LDS ordering: DS ops from one wave execute in order; waitcnt
// guarantees completion, "memory" clobber + wave_barrier stop reordering.
__device__ __forceinline__ void wave_lds_sync(){
  __builtin_amdgcn_wave_barrier();
  __asm__ __volatile__("s_waitcnt lgkmcnt(0)" ::: "memory");
  __builtin_amdgcn_wave_barrier();
}

// 256-pt FFT, radix-4 DIF, one wave, buf = wave-private 256 float2 (swizzled
// addressing). Natural order in and out. No block barriers.
template<int SIGN>
__device__ void wave_fft256w(float2* buf, int lane){
#pragma unroll
  for (int st=0; st<4; ++st){
    const int B = 256 >> (2*st);
    const int Q = B >> 2;
    int m   = lane & (Q-1);
    int blk = lane >> (6 - 2*st);
    int p0  = blk*B + m;
    float2 x0 = buf[swz(p0      )];
    float2 x1 = buf[swz(p0 +   Q)];
    float2 x2 = buf[swz(p0 + 2*Q)];
    float2 x3 = buf[swz(p0 + 3*Q)];
    float2 a  = cadd(x0,x2), bm = csub(x0,x2);
    float2 c  = cadd(x1,x3), d  = csub(x1,x3);
    float2 jd = make_float2(-(float)SIGN*d.y, (float)SIGN*d.x);
    float2 y0 = cadd(a,c);
    float2 y2 = csub(a,c);
    float2 y1 = cadd(bm,jd);
    float2 y3 = csub(bm,jd);
    if (st < 3){
      float ang = (float)SIGN * 6.28318530717958647f * (float)m / (float)B;
      float s1, c1;
      __sincosf(ang, &s1, &c1);
      float2 w1 = make_float2(c1, s1);
      float2 w2 = make_float2(c1*c1 - s1*s1, 2.f*c1*s1);
      float2 w3 = cmul(w1, w2);
      y1 = cmul(y1, w1); y2 = cmul(y2, w2); y3 = cmul(y3, w3);
      buf[swz(p0      )] = y0;
      buf[swz(p0 +   Q)] = y1;
      buf[swz(p0 + 2*Q)] = y2;
      buf[swz(p0 + 3*Q)] = y3;
    } else {
      buf[swz(rev4(4*lane+0))] = y0;
      buf[swz(rev4(4*lane+1))] = y1;
      buf[swz(rev4(4*lane+2))] = y2;
      buf[swz(rev4(4*lane+3))] = y3;
    }
    wave_lds_sync();
  }
}

__global__ void k_scal_init(Scal* sc){
  sc->pap_re = 0.0; sc->pap_im = 0.0; sc->rs_acc = 0.0; sc->rs_old = 0.0;
  sc->done = 0;
}

// W[b][k=s*3+s'][v][u] = (1/65536) * sum_t conj(L_ts) L_ts' mask[b,t,u,v]
__global__ __launch_bounds__(256) void k_w(const float* __restrict__ mask,
                                           const float* __restrict__ tbr,
                                           const float* __restrict__ tbi,
                                           float2* __restrict__ Wb){
  __shared__ float2 wt[9][16][17];
  int tid = threadIdx.x;
  int bx = blockIdx.x;       // 0..255 (16x16 tiles)
  int b  = blockIdx.y;
  int u0 = (bx>>4)<<4, v0 = (bx&15)<<4;
  int u_l = tid>>4, v_l = tid&15;
  int pix = (u0+u_l)*256 + (v0+v_l);
  float d0=0,d1=0,d2=0, o01r=0,o01i=0, o02r=0,o02i=0, o12r=0,o12i=0;
#pragma unroll
  for (int t=0;t<12;t++){
    float m = mask[(size_t)(b*12+t)*HW + pix];
    int lb = (b*12+t)*3;
    float l0r = tbr[lb+0], l0i = tbi[lb+0];
    float l1r = tbr[lb+1], l1i = tbi[lb+1];
    float l2r = tbr[lb+2], l2i = tbi[lb+2];
    d0 += m*(l0r*l0r + l0i*l0i);
    d1 += m*(l1r*l1r + l1i*l1i);
    d2 += m*(l2r*l2r + l2i*l2i);
    o01r += m*(l0r*l1r + l0i*l1i); o01i += m*(l0r*l1i - l0i*l1r);
    o02r += m*(l0r*l2r + l0i*l2i); o02i += m*(l0r*l2i - l0i*l2r);
    o12r += m*(l1r*l2r + l1i*l2i); o12i += m*(l1r*l2i - l1i*l2r);
  }
  const float s = 1.0f/65536.0f;
  wt[0][u_l][v_l] = make_float2(d0*s, 0.f);
  wt[1][u_l][v_l] = make_float2(o01r*s,  o01i*s);
  wt[2][u_l][v_l] = make_float2(o02r*s,  o02i*s);
  wt[3][u_l][v_l] = make_float2(o01r*s, -o01i*s);
  wt[4][u_l][v_l] = make_float2(d1*s, 0.f);
  wt[5][u_l][v_l] = make_float2(o12r*s,  o12i*s);
  wt[6][u_l][v_l] = make_float2(o02r*s, -o02i*s);
  wt[7][u_l][v_l] = make_float2(o12r*s, -o12i*s);
  wt[8][u_l][v_l] = make_float2(d2*s, 0.f);
  __syncthreads();
  int u_l2 = tid&15, v_l2 = tid>>4;
#pragma unroll
  for (int k=0;k<9;k++){
    Wb[ ((size_t)(b*9+k)*256 + (v0+v_l2))*256 + (u0+u_l2) ] = wt[k][u_l2][v_l2];
  }
}

// bufA[(b*10+c)*3+s] = (1/256) * D * sum_t conj(L_ts) * Y[b,t,c]
__global__ __launch_bounds__(256) void k_yhat(const float* __restrict__ kr,
                                              const float* __restrict__ ki,
                                              const float* __restrict__ tbr,
                                              const float* __restrict__ tbi,
                                              float2* __restrict__ bufA){
  int tid = threadIdx.x;
  int pix = blockIdx.x*256 + tid;
  int c = blockIdx.y, b = blockIdx.z;
  float a0r=0,a0i=0,a1r=0,a1i=0,a2r=0,a2i=0;
#pragma unroll
  for (int t=0;t<12;t++){
    size_t off = ((size_t)((b*12+t)*10+c))*HW + pix;
    float yr = kr[off], yi = ki[off];
    int lb = (b*12+t)*3;
    float l0r = tbr[lb+0], l0i = tbi[lb+0];
    float l1r = tbr[lb+1], l1i = tbi[lb+1];
    float l2r = tbr[lb+2], l2i = tbi[lb+2];
    a0r += l0r*yr + l0i*yi;  a0i += l0r*yi - l0i*yr;
    a1r += l1r*yr + l1i*yi;  a1i += l1r*yi - l1i*yr;
    a2r += l2r*yr + l2i*yi;  a2i += l2r*yi - l2i*yr;
  }
  float sgn = (((pix>>8) ^ pix) & 1) ? -1.f : 1.f;
  float s = sgn * (1.0f/256.0f);
  size_t base = ((size_t)(b*10+c))*3*HW + pix;
  bufA[base + 0*(size_t)HW] = make_float2(a0r*s, a0i*s);
  bufA[base + 1*(size_t)HW] = make_float2(a1r*s, a1i*s);
  bufA[base + 2*(size_t)HW] = make_float2(a2r*s, a2i*s);
}

// bvec = lambda * D * MO
__global__ __launch_bounds__(256) void k_bvec0(const float* __restrict__ mor,
                                               const float* __restrict__ moi,
                                               float2* __restrict__ bvec){
  int i = blockIdx.x*256 + threadIdx.x;   // 0..393215
  int pix = i & (HW-1);
  float sgn = (((pix>>8)^pix)&1) ? -1.f : 1.f;
  float s = sgn*LAM;
  bvec[i] = make_float2(s*mor[i], s*moi[i]);
}

// Column pass, in-place on bufA. 4 columns per block, wave w owns column w
// across all 3 s. MODE 0: col-fft only (setup). MODE 1: ifft + W-mix + fft.
// Only 2 block barriers (after coop load, before coop store).
template<int MODE>
__global__ __launch_bounds__(256) void k_colpass(float2* __restrict__ bufA,
                                                 const float2* __restrict__ Wb){
  __shared__ float2 lb[12*256];   // [(s*4+col)][256, swizzled]
  int tid = threadIdx.x, wave = tid>>6, lane = tid&63;
  int j0 = blockIdx.x*4;
  int c = blockIdx.y, b = blockIdx.z;
  for (int s=0;s<3;s++){
    const float2* src = bufA + ((size_t)((b*10+c)*3+s))*HW;
#pragma unroll
    for (int it=0; it<4; it++){
      int idx = it*256 + tid;
      int u = idx>>2, col = idx&3;
      lb[(s*4+col)*256 + swz(u)] = src[u*256 + j0 + col];
    }
  }
  __syncthreads();
  if (MODE==0){
    for (int s=0;s<3;s++)
      wave_fft256w<-1>(&lb[(s*4+wave)*256], lane);
  } else {
    for (int s=0;s<3;s++)
      wave_fft256w<1>(&lb[(s*4+wave)*256], lane);
    const float2* Wp = Wb + (size_t)b*9*HW;
    int v = j0 + wave;
#pragma unroll
    for (int it=0; it<4; it++){
      int u = lane + it*64;
      int su = swz(u);
      float2 x0 = lb[(0*4+wave)*256 + su];
      float2 x1 = lb[(1*4+wave)*256 + su];
      float2 x2 = lb[(2*4+wave)*256 + su];
      size_t wb = (size_t)v*256 + u;
      float2 y0 = cmul(Wp[(size_t)0*HW + wb], x0);
      y0 = cadd(y0, cmul(Wp[(size_t)1*HW + wb], x1));
      y0 = cadd(y0, cmul(Wp[(size_t)2*HW + wb], x2));
      float2 y1 = cmul(Wp[(size_t)3*HW + wb], x0);
      y1 = cadd(y1, cmul(Wp[(size_t)4*HW + wb], x1));
      y1 = cadd(y1, cmul(Wp[(size_t)5*HW + wb], x2));
      float2 y2 = cmul(Wp[(size_t)6*HW + wb], x0);
      y2 = cadd(y2, cmul(Wp[(size_t)7*HW + wb], x1));
      y2 = cadd(y2, cmul(Wp[(size_t)8*HW + wb], x2));
      lb[(0*4+wave)*256 + su] = y0;
      lb[(1*4+wave)*256 + su] = y1;
      lb[(2*4+wave)*256 + su] = y2;
    }
    wave_lds_sync();
    for (int s=0;s<3;s++)
      wave_fft256w<-1>(&lb[(s*4+wave)*256], lane);
  }
  __syncthreads();
  for (int s=0;s<3;s++){
    float2* dst = bufA + ((size_t)((b*10+c)*3+s))*HW;
#pragma unroll
    for (int it=0; it<4; it++){
      int idx = it*256 + tid;
      int u = idx>>2, col = idx&3;
      dst[u*256 + j0 + col] = lb[(s*4+col)*256 + swz(u)];
    }
  }
}

// bufA[(b,c,s)] rows = row-ifft(S_c * p_s). Wave-private, no block barriers.
__global__ __launch_bounds__(256) void k_rowifft(const float2* __restrict__ p,
                                                 const float* __restrict__ sr_,
                                                 const float* __restrict__ si_,
                                                 float2* __restrict__ bufA){
  __shared__ float2 lb[4*256];
  int tid = threadIdx.x, wave = tid>>6, lane = tid&63;
  int row = blockIdx.x*4 + wave;
  int cs = blockIdx.y, b = blockIdx.z;
  int c = cs/3, s = cs - 3*c;
  const float2* pp = p + (size_t)(b*3+s)*HW + (size_t)row*256;
  const float*  sr = sr_ + (size_t)(b*10+c)*HW + (size_t)row*256;
  const float*  si = si_ + (size_t)(b*10+c)*HW + (size_t)row*256;
  float2* lw = &lb[wave*256];
#pragma unroll
  for (int q=0;q<4;q++){
    int k = lane + 64*q;
    float2 sv = make_float2(sr[k], si[k]);
    lw[swz(k)] = cmul(sv, pp[k]);
  }
  wave_lds_sync();
  wave_fft256w<1>(lw, lane);
  float2* dst = bufA + (size_t)((b*10+c)*3+s)*HW + (size_t)row*256;
#pragma unroll
  for (int q=0;q<4;q++){
    int k = lane + 64*q;
    dst[k] = lw[swz(k)];
  }
}

// in-place forward row-fft on bufA[(b,c,s)]. Wave-private, no block barriers.
__global__ __launch_bounds__(256) void k_rowfft2(float2* __restrict__ bufA){
  __shared__ float2 lb[4*256];
  int tid = threadIdx.x, wave = tid>>6, lane = tid&63;
  int row = blockIdx.x*4 + wave;
  int cs = blockIdx.y, b = blockIdx.z;
  int c = cs/3, s = cs - 3*c;
  float2* ptr = bufA + (size_t)((b*10+c)*3+s)*HW + (size_t)row*256;
  float2* lw = &lb[wave*256];
#pragma unroll
  for (int q=0;q<4;q++){
    int k = lane + 64*q;
    lw[swz(k)] = ptr[k];
  }
  wave_lds_sync();
  wave_fft256w<-1>(lw, lane);
#pragma unroll
  for (int q=0;q<4;q++){
    int k = lane + 64*q;
    ptr[k] = lw[swz(k)];
  }
}

// out[i] = sum_c conj(S_c)*bufA[b,c,s] + ascale*addend[i],  i in [0, 6*HW)
// SETUP=1: accumulate |out|^2 -> rs_acc.  SETUP=0: conj(addend).out -> pap,
// and zero rs_acc for the upcoming upzr reduction.
template<int SETUP>
__global__ __launch_bounds__(256) void k_combine(const float2* __restrict__ bufA,
                                                 const float* __restrict__ sr_,
                                                 const float* __restrict__ si_,
                                                 const float2* __restrict__ addend,
                                                 float ascale,
                                                 float2* __restrict__ out,
                                                 Scal* sc){
  __shared__ double sd[4], sd2[4];
  int tid = threadIdx.x;
  int i = blockIdx.x*256 + tid;          // [0, 393216)
  int pix = i & (HW-1);
  int bs = i >> 16;                      // b*3+s, [0,6)
  int b = bs/3, s = bs - 3*b;
  if (!SETUP && i==0) sc->rs_acc = 0.0;
  float2 acc = make_float2(0.f, 0.f);
#pragma unroll
  for (int c=0;c<10;c++){
    size_t fo = ((size_t)((b*10+c)*3+s))*HW + pix;
    size_t so = ((size_t)(b*10+c))*HW + pix;
    float2 F  = bufA[fo];
    float2 sv = make_float2(sr_[so], si_[so]);
    acc = cadd(acc, cmulj(sv, F));
  }
  float2 av = addend[i];
  acc.x += ascale*av.x; acc.y += ascale*av.y;
  out[i] = acc;
  double dre, dim = 0.0;
  if (SETUP){
    dre = (double)acc.x*acc.x + (double)acc.y*acc.y;
  } else {
    dre = (double)av.x*acc.x + (double)av.y*acc.y;
    dim = (double)av.x*acc.y - (double)av.y*acc.x;
  }
  for (int off=32; off>0; off>>=1){
    dre += __shfl_down(dre, off, 64);
    if (!SETUP) dim += __shfl_down(dim, off, 64);
  }
  if ((tid&63)==0){ sd[tid>>6] = dre; sd2[tid>>6] = dim; }
  __syncthreads();
  if (tid==0){
    double tre = sd[0]+sd[1]+sd[2]+sd[3];
    if (SETUP){
      atomicAdd(&sc->rs_acc, tre);
    } else {
      double tim = sd2[0]+sd2[1]+sd2[2]+sd2[3];
      atomicAdd(&sc->pap_re, tre);
      atomicAdd(&sc->pap_im, tim);
    }
  }
}

__global__ __launch_bounds__(256) void k_cginit(const float2* __restrict__ bvec,
                                                float2* __restrict__ z,
                                                float2* __restrict__ r,
                                                float2* __restrict__ p,
                                                Scal* sc){
  int i = blockIdx.x*256 + threadIdx.x;
  float2 bv = bvec[i];
  z[i] = make_float2(0.f,0.f);
  r[i] = bv; p[i] = bv;
  if (i==0){ sc->rs_old = sc->rs_acc; sc->pap_re=0.0; sc->pap_im=0.0; }
}

__global__ __launch_bounds__(256) void k_upzr(float2* __restrict__ z,
                                              float2* __restrict__ r,
                                              const float2* __restrict__ p,
                                              const float2* __restrict__ Ap,
                                              Scal* sc){
  __shared__ double sd[4];
  int tid = threadIdx.x;
  int i = blockIdx.x*256 + tid;
  int done = sc->done;
  double local = 0.0;
  if (!done){
    double dre = sc->pap_re + 1e-20, dim = sc->pap_im;
    double den = dre*dre + dim*dim;
    double rs = sc->rs_old;
    float2 alpha = make_float2((float)( rs*dre/den), (float)(-rs*dim/den));
    float2 pv = p[i], apv = Ap[i];
    float2 zv = cadd(z[i], cmul(alpha, pv));
    float2 rv = csub(r[i], cmul(alpha, apv));
    z[i] = zv; r[i] = rv;
    local = (double)rv.x*rv.x + (double)rv.y*rv.y;
  }
  for (int off=32; off>0; off>>=1) local += __shfl_down(local, off, 64);
  if ((tid&63)==0) sd[tid>>6] = local;
  __syncthreads();
  if (tid==0 && !done){
    atomicAdd(&sc->rs_acc, sd[0]+sd[1]+sd[2]+sd[3]);
  }
}

__global__ __launch_bounds__(256) void k_upp(float2* __restrict__ p,
                                             const float2* __restrict__ r,
                                             Scal* sc){
  if (sc->done) return;
  int i = blockIdx.x*256 + threadIdx.x;
  float beta = (float)(sc->rs_acc / (sc->rs_old + 1e-20));
  float2 pv = p[i];
  p[i] = make_float2(r[i].x + beta*pv.x, r[i].y + beta*pv.y);
}

__global__ void k_beta(Scal* sc){
  if (!sc->done){
    sc->rs_old = sc->rs_acc;
    if (fabs(sc->rs_old) < 1e-10) sc->done = 1;
  }
  sc->pap_re = 0.0; sc->pap_im = 0.0;
}

__global__ __launch_bounds__(256) void k_out(const float2* __restrict__ z,
                                             float* __restrict__ out){
  int i = blockIdx.x*256 + threadIdx.x;
  int pix = i & (HW-1);
  float sgn = (((pix>>8)^pix)&1) ? -1.f : 1.f;
  float2 zv = z[i];
  out[2*i]   = sgn*zv.x;
  out[2*i+1] = sgn*zv.y;
}

extern "C" void kernel_launch(void* const* d_in, const int* in_sizes, int n_in,
                              void* d_out, int out_size, void* d_ws, size_t ws_size,
                              hipStream_t stream){
  const float* kr   = (const float*)d_in[0];
  const float* ki   = (const float*)d_in[1];
  const float* mor  = (const float*)d_in[2];
  const float* moi  = (const float*)d_in[3];
  const float* sr   = (const float*)d_in[4];
  const float* si   = (const float*)d_in[5];
  const float* tbr  = (const float*)d_in[6];
  const float* tbi  = (const float*)d_in[7];
  const float* mask = (const float*)d_in[8];
  float* out = (float*)d_out;

  float2* ws   = (float2*)d_ws;
  float2* bufA = ws;                 // 60*HW float2
  float2* Wb   = ws + 3932160;       // 2*9*HW
  float2* bvec = ws + 5111808;
  float2* z    = ws + 5505024;
  float2* r    = ws + 5898240;
  float2* p    = ws + 6291456;
  float2* Ap   = ws + 6684672;
  Scal*   sc   = (Scal*)(ws + 7077888);

  k_scal_init<<<dim3(1),dim3(1),0,stream>>>(sc);
  k_w<<<dim3(256,2),dim3(256),0,stream>>>(mask, tbr, tbi, Wb);
  k_yhat<<<dim3(256,10,2),dim3(256),0,stream>>>(kr, ki, tbr, tbi, bufA);
  k_bvec0<<<dim3(1536),dim3(256),0,stream>>>(mor, moi, bvec);
  k_colpass<0><<<dim3(64,10,2),dim3(256),0,stream>>>(bufA, Wb);
  k_rowfft2<<<dim3(64,30,2),dim3(256),0,stream>>>(bufA);
  k_combine<1><<<dim3(1536),dim3(256),0,stream>>>(bufA, sr, si, bvec, 1.0f,
                                                  bvec, sc);
  k_cginit<<<dim3(1536),dim3(256),0,stream>>>(bvec, z, r, p, sc);
  for (int it=0; it<6; ++it){
    k_rowifft<<<dim3(64,30,2),dim3(256),0,stream>>>(p, sr, si, bufA);
    k_colpass<1><<<dim3(64,10,2),dim3(256),0,stream>>>(bufA, Wb);
    k_rowfft2<<<dim3(64,30,2),dim3(256),0,stream>>>(bufA);
    k_combine<0><<<dim3(1536),dim3(256),0,stream>>>(bufA, sr, si, p, LAM,
                                                    Ap, sc);
    k_upzr<<<dim3(1536),dim3(256),0,stream>>>(z, r, p, Ap, sc);
    k_upp<<<dim3(1536),dim3(256),0,stream>>>(p, r, sc);
    k_beta<<<dim3(1),dim3(1),0,stream>>>(sc);
  }
  k_out<<<dim3(1536),dim3(256),0,stream>>>(z, out);
}

// Round 4
// 871.898 us; speedup vs baseline: 1.1991x; 1.1965x over previous
//
// R4: fusion round.
//  - k_spfft: S*p multiply + row-ifft, one block per (row,b), 30 planes in
//    61KB LDS, wave-local FFT+store (p read 1x not 10x)
//  - k_rowcomb: row-fft + conj(S) coil-combine + addend + dot, one block per
//    (row,b) (replaces rowfft2+combine; kills 126MB/iter of LLC traffic)
//  - colpass: 8 cols/block, stride-257 slices, 64B global segments; mix is
//    wave-local (col%4==wave for all s)
//  - k_beta folded into k_upp (last-block atomic counter); scal_init into
//    k_w; bvec0 into k_rowcomb<1>. Dispatches 45 -> 36.
//  - k_yhat: float2 loads, float4 stores
#include <hip/hip_runtime.h>
#include <math.h>

#define HW 65536
#define LAM 0.05f

struct Scal {
  double pap_re, pap_im, rs_acc, rs_old;
  int done, cnt;
};

__device__ __forceinline__ float2 cadd(float2 a, float2 b){ return make_float2(a.x+b.x, a.y+b.y); }
__device__ __forceinline__ float2 csub(float2 a, float2 b){ return make_float2(a.x-b.x, a.y-b.y); }
__device__ __forceinline__ float2 cmul(float2 a, float2 b){
  return make_float2(a.x*b.x - a.y*b.y, a.x*b.y + a.y*b.x);
}
__device__ __forceinline__ float2 cmulj(float2 a, float2 b){ // conj(a)*b
  return make_float2(a.x*b.x + a.y*b.y, a.x*b.y - a.y*b.x);
}
__device__ __forceinline__ int rev4(int p){
  return ((p&3)<<6) | (((p>>2)&3)<<4) | (((p>>4)&3)<<2) | ((p>>6)&3);
}
__device__ __forceinline__ int swz(int p){ return p ^ (p>>4); }

__device__ __forceinline__ void wave_lds_sync(){
  __builtin_amdgcn_wave_barrier();
  __asm__ __volatile__("s_waitcnt lgkmcnt(0)" ::: "memory");
  __builtin_amdgcn_wave_barrier();
}

// 256-pt radix-4 DIF FFT, one wave, swizzled wave-private LDS slice.
// Natural order in/out. Ends with wave_lds_sync.
template<int SIGN>
__device__ void wave_fft256w(float2* buf, int lane){
#pragma unroll
  for (int st=0; st<4; ++st){
    const int B = 256 >> (2*st);
    const int Q = B >> 2;
    int m   = lane & (Q-1);
    int blk = lane >> (6 - 2*st);
    int p0  = blk*B + m;
    float2 x0 = buf[swz(p0      )];
    float2 x1 = buf[swz(p0 +   Q)];
    float2 x2 = buf[swz(p0 + 2*Q)];
    float2 x3 = buf[swz(p0 + 3*Q)];
    float2 a  = cadd(x0,x2), bm = csub(x0,x2);
    float2 c  = cadd(x1,x3), d  = csub(x1,x3);
    float2 jd = make_float2(-(float)SIGN*d.y, (float)SIGN*d.x);
    float2 y0 = cadd(a,c);
    float2 y2 = csub(a,c);
    float2 y1 = cadd(bm,jd);
    float2 y3 = csub(bm,jd);
    if (st < 3){
      float ang = (float)SIGN * 6.28318530717958647f * (float)m / (float)B;
      float s1, c1;
      __sincosf(ang, &s1, &c1);
      float2 w1 = make_float2(c1, s1);
      float2 w2 = make_float2(c1*c1 - s1*s1, 2.f*c1*s1);
      float2 w3 = cmul(w1, w2);
      y1 = cmul(y1, w1); y2 = cmul(y2, w2); y3 = cmul(y3, w3);
      buf[swz(p0      )] = y0;
      buf[swz(p0 +   Q)] = y1;
      buf[swz(p0 + 2*Q)] = y2;
      buf[swz(p0 + 3*Q)] = y3;
    } else {
      buf[swz(rev4(4*lane+0))] = y0;
      buf[swz(rev4(4*lane+1))] = y1;
      buf[swz(rev4(4*lane+2))] = y2;
      buf[swz(rev4(4*lane+3))] = y3;
    }
    wave_lds_sync();
  }
}

// W[b][k=s*3+s'][v][u] = (1/65536) sum_t conj(L_ts) L_ts' mask[b,t,u,v]
// Also initializes the Scal block (block 0 only).
__global__ __launch_bounds__(256) void k_w(const float* __restrict__ mask,
                                           const float* __restrict__ tbr,
                                           const float* __restrict__ tbi,
                                           float2* __restrict__ Wb,
                                           Scal* sc){
  if (blockIdx.x==0 && blockIdx.y==0 && threadIdx.x==0){
    sc->pap_re=0.0; sc->pap_im=0.0; sc->rs_acc=0.0; sc->rs_old=0.0;
    sc->done=0; sc->cnt=0;
  }
  __shared__ float2 wt[9][16][17];
  int tid = threadIdx.x;
  int bx = blockIdx.x;
  int b  = blockIdx.y;
  int u0 = (bx>>4)<<4, v0 = (bx&15)<<4;
  int u_l = tid>>4, v_l = tid&15;
  int pix = (u0+u_l)*256 + (v0+v_l);
  float d0=0,d1=0,d2=0, o01r=0,o01i=0, o02r=0,o02i=0, o12r=0,o12i=0;
#pragma unroll
  for (int t=0;t<12;t++){
    float m = mask[(size_t)(b*12+t)*HW + pix];
    int lb = (b*12+t)*3;
    float l0r = tbr[lb+0], l0i = tbi[lb+0];
    float l1r = tbr[lb+1], l1i = tbi[lb+1];
    float l2r = tbr[lb+2], l2i = tbi[lb+2];
    d0 += m*(l0r*l0r + l0i*l0i);
    d1 += m*(l1r*l1r + l1i*l1i);
    d2 += m*(l2r*l2r + l2i*l2i);
    o01r += m*(l0r*l1r + l0i*l1i); o01i += m*(l0r*l1i - l0i*l1r);
    o02r += m*(l0r*l2r + l0i*l2i); o02i += m*(l0r*l2i - l0i*l2r);
    o12r += m*(l1r*l2r + l1i*l2i); o12i += m*(l1r*l2i - l1i*l2r);
  }
  const float s = 1.0f/65536.0f;
  wt[0][u_l][v_l] = make_float2(d0*s, 0.f);
  wt[1][u_l][v_l] = make_float2(o01r*s,  o01i*s);
  wt[2][u_l][v_l] = make_float2(o02r*s,  o02i*s);
  wt[3][u_l][v_l] = make_float2(o01r*s, -o01i*s);
  wt[4][u_l][v_l] = make_float2(d1*s, 0.f);
  wt[5][u_l][v_l] = make_float2(o12r*s,  o12i*s);
  wt[6][u_l][v_l] = make_float2(o02r*s, -o02i*s);
  wt[7][u_l][v_l] = make_float2(o12r*s, -o12i*s);
  wt[8][u_l][v_l] = make_float2(d2*s, 0.f);
  __syncthreads();
  int u_l2 = tid&15, v_l2 = tid>>4;
#pragma unroll
  for (int k=0;k<9;k++){
    Wb[ ((size_t)(b*9+k)*256 + (v0+v_l2))*256 + (u0+u_l2) ] = wt[k][u_l2][v_l2];
  }
}

// bufA[(b*10+c)*3+s] = (1/256) * D * sum_t conj(L_ts) * Y[b,t,c]
// 2 pixels per thread; float2 loads, float4 stores.
__global__ __launch_bounds__(256) void k_yhat(const float* __restrict__ kr,
                                              const float* __restrict__ ki,
                                              const float* __restrict__ tbr,
                                              const float* __restrict__ tbi,
                                              float2* __restrict__ bufA){
  int tid = threadIdx.x;
  int pr  = blockIdx.x*256 + tid;   // pair index
  int pix = pr*2;
  int c = blockIdx.y, b = blockIdx.z;
  float aer[3]={0,0,0}, aei[3]={0,0,0}, bor[3]={0,0,0}, boi[3]={0,0,0};
#pragma unroll
  for (int t=0;t<12;t++){
    size_t off = ((size_t)((b*12+t)*10+c))*HW + pix;
    float2 yr = *(const float2*)(kr+off);
    float2 yi = *(const float2*)(ki+off);
    int lb = (b*12+t)*3;
#pragma unroll
    for (int s=0;s<3;s++){
      float lr = tbr[lb+s], li = tbi[lb+s];
      aer[s] += lr*yr.x + li*yi.x;  aei[s] += lr*yi.x - li*yr.x;
      bor[s] += lr*yr.y + li*yi.y;  boi[s] += lr*yi.y - li*yr.y;
    }
  }
  float sg0 = (((pix>>8) ^ pix) & 1) ? -1.f : 1.f;
  float s0 = sg0*(1.0f/256.0f), s1 = -s0;
  size_t base = ((size_t)(b*10+c))*3*HW + pix;
#pragma unroll
  for (int s=0;s<3;s++){
    float4 o = make_float4(aer[s]*s0, aei[s]*s0, bor[s]*s1, boi[s]*s1);
    *(float4*)(&bufA[base + (size_t)s*HW]) = o;
  }
}

// Column pass, in-place on bufA. 8 cols/block, stride-257 LDS slices.
// MODE 0: col-fft only. MODE 1: col-ifft + W mix + col-fft (mix wave-local).
template<int MODE>
__global__ __launch_bounds__(256) void k_colpass(float2* __restrict__ bufA,
                                                 const float2* __restrict__ Wb){
  __shared__ float2 lb[24*257];
  int tid = threadIdx.x, wave = tid>>6, lane = tid&63;
  int j0 = blockIdx.x*8;
  int c = blockIdx.y, b = blockIdx.z;
  for (int s=0;s<3;s++){
    const float2* src = bufA + ((size_t)(b*30 + c*3 + s))*HW;
#pragma unroll
    for (int it=0; it<8; it++){
      int idx = it*256 + tid;
      int u = idx>>3, col = idx&7;
      lb[(s*8+col)*257 + swz(u)] = src[u*256 + j0 + col];
    }
  }
  __syncthreads();
  if (MODE==0){
    for (int fc=wave; fc<24; fc+=4)
      wave_fft256w<-1>(&lb[fc*257], lane);
  } else {
    for (int fc=wave; fc<24; fc+=4)
      wave_fft256w<1>(&lb[fc*257], lane);
    // mix: wave owns cols {wave, wave+4} for all 3 s (fc%4 == col%4)
    const float2* Wp = Wb + (size_t)b*9*HW;
#pragma unroll
    for (int cc=0; cc<2; cc++){
      int col = wave + 4*cc;
      int v = j0 + col;
#pragma unroll
      for (int it=0; it<4; it++){
        int u = lane + it*64;
        int su = swz(u);
        float2 x0 = lb[(0*8+col)*257 + su];
        float2 x1 = lb[(1*8+col)*257 + su];
        float2 x2 = lb[(2*8+col)*257 + su];
        size_t wb = (size_t)v*256 + u;
        float2 y0 = cmul(Wp[(size_t)0*HW + wb], x0);
        y0 = cadd(y0, cmul(Wp[(size_t)1*HW + wb], x1));
        y0 = cadd(y0, cmul(Wp[(size_t)2*HW + wb], x2));
        float2 y1 = cmul(Wp[(size_t)3*HW + wb], x0);
        y1 = cadd(y1, cmul(Wp[(size_t)4*HW + wb], x1));
        y1 = cadd(y1, cmul(Wp[(size_t)5*HW + wb], x2));
        float2 y2 = cmul(Wp[(size_t)6*HW + wb], x0);
        y2 = cadd(y2, cmul(Wp[(size_t)7*HW + wb], x1));
        y2 = cadd(y2, cmul(Wp[(size_t)8*HW + wb], x2));
        lb[(0*8+col)*257 + su] = y0;
        lb[(1*8+col)*257 + su] = y1;
        lb[(2*8+col)*257 + su] = y2;
      }
    }
    wave_lds_sync();
    for (int fc=wave; fc<24; fc+=4)
      wave_fft256w<-1>(&lb[fc*257], lane);
  }
  __syncthreads();
  for (int s=0;s<3;s++){
    float2* dst = bufA + ((size_t)(b*30 + c*3 + s))*HW;
#pragma unroll
    for (int it=0; it<8; it++){
      int idx = it*256 + tid;
      int u = idx>>3, col = idx&7;
      dst[u*256 + j0 + col] = lb[(s*8+col)*257 + swz(u)];
    }
  }
}

// Fused S*p multiply + row-ifft. Block = (row r, b); 30 planes in LDS.
__global__ __launch_bounds__(256) void k_spfft(const float2* __restrict__ p,
                                               const float* __restrict__ sr_,
                                               const float* __restrict__ si_,
                                               float2* __restrict__ bufA){
  __shared__ float2 lb[30*257];
  int tid = threadIdx.x, wave = tid>>6, lane = tid&63;
  int r = blockIdx.x, b = blockIdx.y;
  int k = tid;
  float2 pv[3];
#pragma unroll
  for (int s=0;s<3;s++)
    pv[s] = p[(size_t)(b*3+s)*HW + (size_t)r*256 + k];
  int sk = swz(k);
#pragma unroll
  for (int c=0;c<10;c++){
    size_t so = (size_t)(b*10+c)*HW + (size_t)r*256 + k;
    float2 sv = make_float2(sr_[so], si_[so]);
#pragma unroll
    for (int s=0;s<3;s++)
      lb[(c*3+s)*257 + sk] = cmul(sv, pv[s]);
  }
  __syncthreads();
  for (int pl=wave; pl<30; pl+=4){
    float2* lw = &lb[pl*257];
    wave_fft256w<1>(lw, lane);
    float2* dst = bufA + (size_t)(b*30+pl)*HW + (size_t)r*256;
#pragma unroll
    for (int q=0;q<4;q++){
      int kk = lane + 64*q;
      dst[kk] = lw[swz(kk)];   // wave-local; fft ended with wave_lds_sync
    }
  }
}

// Fused row-fft + conj(S) combine + addend + dot. Block = (row r, b).
// SETUP=1: addend = lambda*D*MO (read from mor/moi); out=bvec; |out|^2->rs_acc
// SETUP=0: addend = p (pad); out = combined + LAM*p = Ap; conj(p).Ap -> pap;
//          also zeroes rs_acc (block r==0,b==0) for the upcoming upzr.
template<int SETUP>
__global__ __launch_bounds__(256) void k_rowcomb(const float2* __restrict__ bufA,
                                                 const float* __restrict__ sr_,
                                                 const float* __restrict__ si_,
                                                 const float* __restrict__ mor,
                                                 const float* __restrict__ moi,
                                                 const float2* __restrict__ pad,
                                                 float2* __restrict__ out,
                                                 Scal* sc){
  __shared__ float2 lb[30*257];
  __shared__ double sd[4], sd2[4];
  int tid = threadIdx.x, wave = tid>>6, lane = tid&63;
  int r = blockIdx.x, b = blockIdx.y;
  if (!SETUP && r==0 && b==0 && tid==0) sc->rs_acc = 0.0;
  // wave loads + ffts its own planes
  for (int pl=wave; pl<30; pl+=4){
    const float2* src = bufA + (size_t)(b*30+pl)*HW + (size_t)r*256;
    float2* lw = &lb[pl*257];
#pragma unroll
    for (int q=0;q<4;q++){
      int kk = lane + 64*q;
      lw[swz(kk)] = src[kk];
    }
    wave_lds_sync();
    wave_fft256w<-1>(lw, lane);
  }
  __syncthreads();
  // combine over c for column k=tid
  int k = tid, sk = swz(k);
  float2 a0 = make_float2(0,0), a1 = make_float2(0,0), a2 = make_float2(0,0);
#pragma unroll
  for (int c=0;c<10;c++){
    size_t so = (size_t)(b*10+c)*HW + (size_t)r*256 + k;
    float2 sv = make_float2(sr_[so], si_[so]);
    a0 = cadd(a0, cmulj(sv, lb[(c*3+0)*257 + sk]));
    a1 = cadd(a1, cmulj(sv, lb[(c*3+1)*257 + sk]));
    a2 = cadd(a2, cmulj(sv, lb[(c*3+2)*257 + sk]));
  }
  float2 accs[3] = {a0, a1, a2};
  double dre = 0.0, dim = 0.0;
#pragma unroll
  for (int s=0;s<3;s++){
    size_t oi = (size_t)(b*3+s)*HW + (size_t)r*256 + k;
    float2 acc = accs[s];
    if (SETUP){
      float sg = ((r ^ k) & 1) ? -1.f : 1.f;
      float sl = sg * LAM;
      acc.x += sl*mor[oi]; acc.y += sl*moi[oi];
      out[oi] = acc;
      dre += (double)acc.x*acc.x + (double)acc.y*acc.y;
    } else {
      float2 av = pad[oi];
      acc.x += LAM*av.x; acc.y += LAM*av.y;
      out[oi] = acc;
      dre += (double)av.x*acc.x + (double)av.y*acc.y;
      dim += (double)av.x*acc.y - (double)av.y*acc.x;
    }
  }
  for (int off=32; off>0; off>>=1){
    dre += __shfl_down(dre, off, 64);
    if (!SETUP) dim += __shfl_down(dim, off, 64);
  }
  if (lane==0){ sd[wave] = dre; sd2[wave] = dim; }
  __syncthreads();
  if (tid==0){
    double tre = sd[0]+sd[1]+sd[2]+sd[3];
    if (SETUP){
      atomicAdd(&sc->rs_acc, tre);
    } else {
      double tim = sd2[0]+sd2[1]+sd2[2]+sd2[3];
      atomicAdd(&sc->pap_re, tre);
      atomicAdd(&sc->pap_im, tim);
    }
  }
}

__global__ __launch_bounds__(256) void k_cginit(const float2* __restrict__ bvec,
                                                float2* __restrict__ z,
                                                float2* __restrict__ r,
                                                float2* __restrict__ p,
                                                Scal* sc){
  int i = blockIdx.x*256 + threadIdx.x;
  float2 bv = bvec[i];
  z[i] = make_float2(0.f,0.f);
  r[i] = bv; p[i] = bv;
  if (i==0){ sc->rs_old = sc->rs_acc; sc->pap_re=0.0; sc->pap_im=0.0; }
}

__global__ __launch_bounds__(256) void k_upzr(float2* __restrict__ z,
                                              float2* __restrict__ r,
                                              const float2* __restrict__ p,
                                              const float2* __restrict__ Ap,
                                              Scal* sc){
  __shared__ double sd[4];
  int tid = threadIdx.x;
  int i = blockIdx.x*256 + tid;
  int done = sc->done;
  double local = 0.0;
  if (!done){
    double dre = sc->pap_re + 1e-20, dim = sc->pap_im;
    double den = dre*dre + dim*dim;
    double rs = sc->rs_old;
    float2 alpha = make_float2((float)( rs*dre/den), (float)(-rs*dim/den));
    float2 pv = p[i], apv = Ap[i];
    float2 zv = cadd(z[i], cmul(alpha, pv));
    float2 rv = csub(r[i], cmul(alpha, apv));
    z[i] = zv; r[i] = rv;
    local = (double)rv.x*rv.x + (double)rv.y*rv.y;
  }
  for (int off=32; off>0; off>>=1) local += __shfl_down(local, off, 64);
  if ((tid&63)==0) sd[tid>>6] = local;
  __syncthreads();
  if (tid==0 && !done){
    atomicAdd(&sc->rs_acc, sd[0]+sd[1]+sd[2]+sd[3]);
  }
}

// p update + (last block) the old k_beta scalar step.
__global__ __launch_bounds__(256) void k_upp(float2* __restrict__ p,
                                             const float2* __restrict__ r,
                                             Scal* sc){
  __shared__ int amLast;
  int tid = threadIdx.x;
  int i = blockIdx.x*256 + tid;
  int done = sc->done;
  if (!done){
    float beta = (float)(sc->rs_acc / (sc->rs_old + 1e-20));
    float2 pv = p[i];
    p[i] = make_float2(r[i].x + beta*pv.x, r[i].y + beta*pv.y);
  }
  if (tid==0){
    int prev = atomicAdd(&sc->cnt, 1);
    amLast = (prev == (int)gridDim.x - 1);
  }
  __syncthreads();
  if (tid==0 && amLast){
    sc->cnt = 0;
    if (!sc->done){
      sc->rs_old = sc->rs_acc;
      if (fabs(sc->rs_old) < 1e-10) sc->done = 1;
    }
    sc->pap_re = 0.0; sc->pap_im = 0.0;
  }
}

__global__ __launch_bounds__(256) void k_out(const float2* __restrict__ z,
                                             float* __restrict__ out){
  int i = blockIdx.x*256 + threadIdx.x;
  int pix = i & (HW-1);
  float sgn = (((pix>>8)^pix)&1) ? -1.f : 1.f;
  float2 zv = z[i];
  out[2*i]   = sgn*zv.x;
  out[2*i+1] = sgn*zv.y;
}

extern "C" void kernel_launch(void* const* d_in, const int* in_sizes, int n_in,
                              void* d_out, int out_size, void* d_ws, size_t ws_size,
                              hipStream_t stream){
  const float* kr   = (const float*)d_in[0];
  const float* ki   = (const float*)d_in[1];
  const float* mor  = (const float*)d_in[2];
  const float* moi  = (const float*)d_in[3];
  const float* sr   = (const float*)d_in[4];
  const float* si   = (const float*)d_in[5];
  const float* tbr  = (const float*)d_in[6];
  const float* tbi  = (const float*)d_in[7];
  const float* mask = (const float*)d_in[8];
  float* out = (float*)d_out;

  float2* ws   = (float2*)d_ws;
  float2* bufA = ws;                 // 60*HW float2
  float2* Wb   = ws + 3932160;       // 18*HW
  float2* bvec = ws + 5111808;       // 6*HW each below
  float2* z    = ws + 5505024;
  float2* r    = ws + 5898240;
  float2* p    = ws + 6291456;
  float2* Ap   = ws + 6684672;
  Scal*   sc   = (Scal*)(ws + 7077888);

  k_w<<<dim3(256,2),dim3(256),0,stream>>>(mask, tbr, tbi, Wb, sc);
  k_yhat<<<dim3(128,10,2),dim3(256),0,stream>>>(kr, ki, tbr, tbi, bufA);
  k_colpass<0><<<dim3(32,10,2),dim3(256),0,stream>>>(bufA, Wb);
  k_rowcomb<1><<<dim3(256,2),dim3(256),0,stream>>>(bufA, sr, si, mor, moi,
                                                   (const float2*)0, bvec, sc);
  k_cginit<<<dim3(1536),dim3(256),0,stream>>>(bvec, z, r, p, sc);
  for (int it=0; it<6; ++it){
    k_spfft<<<dim3(256,2),dim3(256),0,stream>>>(p, sr, si, bufA);
    k_colpass<1><<<dim3(32,10,2),dim3(256),0,stream>>>(bufA, Wb);
    k_rowcomb<0><<<dim3(256,2),dim3(256),0,stream>>>(bufA, sr, si,
                                                     (const float*)0,
                                                     (const float*)0,
                                                     p, Ap, sc);
    k_upzr<<<dim3(1536),dim3(256),0,stream>>>(z, r, p, Ap, sc);
    k_upp<<<dim3(1536),dim3(256),0,stream>>>(p, r, sc);
  }
  k_out<<<dim3(1536),dim3(256),0,stream>>>(z, out);
}

// Round 5
// 761.292 us; speedup vs baseline: 1.3733x; 1.1453x over previous
//
// R5: latency/ILP round.
//  - wave_fft256w_x2: two interleaved 256-pt FFTs per wave (shared twiddles,
//    2x independent LDS ops per lgkmcnt wait)
//  - k_upp fused into k_spfft (p-update prologue + last-block scalar step,
//    `first` flag per dispatch); dispatches 36 -> 30
//  - float4 global I/O in colpass/rowcomb/spfft; k_yhat 4px/thread float4
#include <hip/hip_runtime.h>
#include <math.h>

#define HW 65536
#define LAM 0.05f

struct Scal {
  double pap_re, pap_im, rs_acc, rs_old;
  int done, cnt;
};

__device__ __forceinline__ float2 cadd(float2 a, float2 b){ return make_float2(a.x+b.x, a.y+b.y); }
__device__ __forceinline__ float2 csub(float2 a, float2 b){ return make_float2(a.x-b.x, a.y-b.y); }
__device__ __forceinline__ float2 cmul(float2 a, float2 b){
  return make_float2(a.x*b.x - a.y*b.y, a.x*b.y + a.y*b.x);
}
__device__ __forceinline__ float2 cmulj(float2 a, float2 b){ // conj(a)*b
  return make_float2(a.x*b.x + a.y*b.y, a.x*b.y - a.y*b.x);
}
__device__ __forceinline__ int rev4(int p){
  return ((p&3)<<6) | (((p>>2)&3)<<4) | (((p>>4)&3)<<2) | ((p>>6)&3);
}
__device__ __forceinline__ int swz(int p){ return p ^ (p>>4); }

__device__ __forceinline__ void wave_lds_sync(){
  __builtin_amdgcn_wave_barrier();
  __asm__ __volatile__("s_waitcnt lgkmcnt(0)" ::: "memory");
  __builtin_amdgcn_wave_barrier();
}

template<int SIGN>
__device__ __forceinline__ void bfly4(float2 x0, float2 x1, float2 x2, float2 x3,
                                      float2& y0, float2& y1, float2& y2, float2& y3){
  float2 a  = cadd(x0,x2), bm = csub(x0,x2);
  float2 c  = cadd(x1,x3), d  = csub(x1,x3);
  float2 jd = make_float2(-(float)SIGN*d.y, (float)SIGN*d.x);
  y0 = cadd(a,c); y2 = csub(a,c); y1 = cadd(bm,jd); y3 = csub(bm,jd);
}

// Two interleaved 256-pt radix-4 DIF FFTs (shared twiddles). Swizzled
// wave-private LDS slices. Natural order in/out. Ends with wave_lds_sync.
template<int SIGN>
__device__ void wave_fft256w_x2(float2* bA, float2* bB, int lane){
#pragma unroll
  for (int st=0; st<4; ++st){
    const int B = 256 >> (2*st);
    const int Q = B >> 2;
    int m   = lane & (Q-1);
    int blk = lane >> (6 - 2*st);
    int p0  = blk*B + m;
    int i0 = swz(p0), i1 = swz(p0+Q), i2 = swz(p0+2*Q), i3 = swz(p0+3*Q);
    float2 xA0=bA[i0], xA1=bA[i1], xA2=bA[i2], xA3=bA[i3];
    float2 xB0=bB[i0], xB1=bB[i1], xB2=bB[i2], xB3=bB[i3];
    float2 yA0,yA1,yA2,yA3, yB0,yB1,yB2,yB3;
    bfly4<SIGN>(xA0,xA1,xA2,xA3, yA0,yA1,yA2,yA3);
    bfly4<SIGN>(xB0,xB1,xB2,xB3, yB0,yB1,yB2,yB3);
    if (st < 3){
      float ang = (float)SIGN * 6.28318530717958647f * (float)m / (float)B;
      float s1, c1;
      __sincosf(ang, &s1, &c1);
      float2 w1 = make_float2(c1, s1);
      float2 w2 = make_float2(c1*c1 - s1*s1, 2.f*c1*s1);
      float2 w3 = cmul(w1, w2);
      bA[i0]=yA0; bA[i1]=cmul(yA1,w1); bA[i2]=cmul(yA2,w2); bA[i3]=cmul(yA3,w3);
      bB[i0]=yB0; bB[i1]=cmul(yB1,w1); bB[i2]=cmul(yB2,w2); bB[i3]=cmul(yB3,w3);
    } else {
      int r0=swz(rev4(4*lane+0)), r1=swz(rev4(4*lane+1));
      int r2=swz(rev4(4*lane+2)), r3=swz(rev4(4*lane+3));
      bA[r0]=yA0; bA[r1]=yA1; bA[r2]=yA2; bA[r3]=yA3;
      bB[r0]=yB0; bB[r1]=yB1; bB[r2]=yB2; bB[r3]=yB3;
    }
    wave_lds_sync();
  }
}

// W[b][k=s*3+s'][v][u] = (1/65536) sum_t conj(L_ts) L_ts' mask[b,t,u,v]
__global__ __launch_bounds__(256) void k_w(const float* __restrict__ mask,
                                           const float* __restrict__ tbr,
                                           const float* __restrict__ tbi,
                                           float2* __restrict__ Wb,
                                           Scal* sc){
  if (blockIdx.x==0 && blockIdx.y==0 && threadIdx.x==0){
    sc->pap_re=0.0; sc->pap_im=0.0; sc->rs_acc=0.0; sc->rs_old=0.0;
    sc->done=0; sc->cnt=0;
  }
  __shared__ float2 wt[9][16][17];
  int tid = threadIdx.x;
  int bx = blockIdx.x;
  int b  = blockIdx.y;
  int u0 = (bx>>4)<<4, v0 = (bx&15)<<4;
  int u_l = tid>>4, v_l = tid&15;
  int pix = (u0+u_l)*256 + (v0+v_l);
  float d0=0,d1=0,d2=0, o01r=0,o01i=0, o02r=0,o02i=0, o12r=0,o12i=0;
#pragma unroll
  for (int t=0;t<12;t++){
    float m = mask[(size_t)(b*12+t)*HW + pix];
    int lb = (b*12+t)*3;
    float l0r = tbr[lb+0], l0i = tbi[lb+0];
    float l1r = tbr[lb+1], l1i = tbi[lb+1];
    float l2r = tbr[lb+2], l2i = tbi[lb+2];
    d0 += m*(l0r*l0r + l0i*l0i);
    d1 += m*(l1r*l1r + l1i*l1i);
    d2 += m*(l2r*l2r + l2i*l2i);
    o01r += m*(l0r*l1r + l0i*l1i); o01i += m*(l0r*l1i - l0i*l1r);
    o02r += m*(l0r*l2r + l0i*l2i); o02i += m*(l0r*l2i - l0i*l2r);
    o12r += m*(l1r*l2r + l1i*l2i); o12i += m*(l1r*l2i - l1i*l2r);
  }
  const float s = 1.0f/65536.0f;
  wt[0][u_l][v_l] = make_float2(d0*s, 0.f);
  wt[1][u_l][v_l] = make_float2(o01r*s,  o01i*s);
  wt[2][u_l][v_l] = make_float2(o02r*s,  o02i*s);
  wt[3][u_l][v_l] = make_float2(o01r*s, -o01i*s);
  wt[4][u_l][v_l] = make_float2(d1*s, 0.f);
  wt[5][u_l][v_l] = make_float2(o12r*s,  o12i*s);
  wt[6][u_l][v_l] = make_float2(o02r*s, -o02i*s);
  wt[7][u_l][v_l] = make_float2(o12r*s, -o12i*s);
  wt[8][u_l][v_l] = make_float2(d2*s, 0.f);
  __syncthreads();
  int u_l2 = tid&15, v_l2 = tid>>4;
#pragma unroll
  for (int k=0;k<9;k++){
    Wb[ ((size_t)(b*9+k)*256 + (v0+v_l2))*256 + (u0+u_l2) ] = wt[k][u_l2][v_l2];
  }
}

// bufA[(b*10+c)*3+s] = (1/256) * D * sum_t conj(L_ts) * Y[b,t,c]
// 4 pixels per thread; float4 loads and stores.
__global__ __launch_bounds__(256) void k_yhat(const float* __restrict__ kr,
                                              const float* __restrict__ ki,
                                              const float* __restrict__ tbr,
                                              const float* __restrict__ tbi,
                                              float2* __restrict__ bufA){
  int tid = threadIdx.x;
  int pix = (blockIdx.x*256 + tid)*4;
  int c = blockIdx.y, b = blockIdx.z;
  float ar[3][4], ai[3][4];
#pragma unroll
  for (int s=0;s<3;s++)
#pragma unroll
    for (int j=0;j<4;j++){ ar[s][j]=0.f; ai[s][j]=0.f; }
#pragma unroll
  for (int t=0;t<12;t++){
    size_t off = ((size_t)((b*12+t)*10+c))*HW + pix;
    float4 yr = *(const float4*)(kr+off);
    float4 yi = *(const float4*)(ki+off);
    float yrv[4] = {yr.x, yr.y, yr.z, yr.w};
    float yiv[4] = {yi.x, yi.y, yi.z, yi.w};
    int lb = (b*12+t)*3;
#pragma unroll
    for (int s=0;s<3;s++){
      float lr = tbr[lb+s], li = tbi[lb+s];
#pragma unroll
      for (int j=0;j<4;j++){
        ar[s][j] += lr*yrv[j] + li*yiv[j];
        ai[s][j] += lr*yiv[j] - li*yrv[j];
      }
    }
  }
  float sg0 = (((pix>>8) ^ pix) & 1) ? -1.f : 1.f;
  float sg[4] = { sg0*(1.f/256.f), -sg0*(1.f/256.f), sg0*(1.f/256.f), -sg0*(1.f/256.f) };
  size_t base = ((size_t)(b*10+c))*3*HW + pix;
#pragma unroll
  for (int s=0;s<3;s++){
    float4 o0 = make_float4(ar[s][0]*sg[0], ai[s][0]*sg[0], ar[s][1]*sg[1], ai[s][1]*sg[1]);
    float4 o1 = make_float4(ar[s][2]*sg[2], ai[s][2]*sg[2], ar[s][3]*sg[3], ai[s][3]*sg[3]);
    *(float4*)(&bufA[base + (size_t)s*HW])     = o0;
    *(float4*)(&bufA[base + (size_t)s*HW + 2]) = o1;
  }
}

// Column pass, in-place on bufA. 8 cols/block, stride-257 LDS slices.
// Wave w owns cols {2w, 2w+1} across all 3 s (x2-FFT pairing keeps the mix
// wave-local). MODE 0: col-fft. MODE 1: col-ifft + W mix + col-fft.
template<int MODE>
__global__ __launch_bounds__(256) void k_colpass(float2* __restrict__ bufA,
                                                 const float2* __restrict__ Wb){
  __shared__ float2 lb[24*257];
  int tid = threadIdx.x, wave = tid>>6, lane = tid&63;
  int j0 = blockIdx.x*8;
  int c = blockIdx.y, b = blockIdx.z;
  for (int s=0;s<3;s++){
    const float2* src = bufA + ((size_t)(b*30 + c*3 + s))*HW;
#pragma unroll
    for (int it=0; it<4; it++){
      int idx = it*256 + tid;
      int u = idx>>2, cp = idx&3;
      float4 v = *(const float4*)(src + u*256 + j0 + 2*cp);
      lb[(s*8+2*cp  )*257 + swz(u)] = make_float2(v.x, v.y);
      lb[(s*8+2*cp+1)*257 + swz(u)] = make_float2(v.z, v.w);
    }
  }
  __syncthreads();
  if (MODE==0){
    for (int fc=wave*2; fc<24; fc+=8)
      wave_fft256w_x2<-1>(&lb[fc*257], &lb[(fc+1)*257], lane);
  } else {
    for (int fc=wave*2; fc<24; fc+=8)
      wave_fft256w_x2<1>(&lb[fc*257], &lb[(fc+1)*257], lane);
    const float2* Wp = Wb + (size_t)b*9*HW;
#pragma unroll
    for (int cc=0; cc<2; cc++){
      int col = wave*2 + cc;
      int v = j0 + col;
#pragma unroll
      for (int it=0; it<4; it++){
        int u = lane + it*64;
        int su = swz(u);
        float2 x0 = lb[(0*8+col)*257 + su];
        float2 x1 = lb[(1*8+col)*257 + su];
        float2 x2 = lb[(2*8+col)*257 + su];
        size_t wb = (size_t)v*256 + u;
        float2 y0 = cmul(Wp[(size_t)0*HW + wb], x0);
        y0 = cadd(y0, cmul(Wp[(size_t)1*HW + wb], x1));
        y0 = cadd(y0, cmul(Wp[(size_t)2*HW + wb], x2));
        float2 y1 = cmul(Wp[(size_t)3*HW + wb], x0);
        y1 = cadd(y1, cmul(Wp[(size_t)4*HW + wb], x1));
        y1 = cadd(y1, cmul(Wp[(size_t)5*HW + wb], x2));
        float2 y2 = cmul(Wp[(size_t)6*HW + wb], x0);
        y2 = cadd(y2, cmul(Wp[(size_t)7*HW + wb], x1));
        y2 = cadd(y2, cmul(Wp[(size_t)8*HW + wb], x2));
        lb[(0*8+col)*257 + su] = y0;
        lb[(1*8+col)*257 + su] = y1;
        lb[(2*8+col)*257 + su] = y2;
      }
    }
    wave_lds_sync();
    for (int fc=wave*2; fc<24; fc+=8)
      wave_fft256w_x2<-1>(&lb[fc*257], &lb[(fc+1)*257], lane);
  }
  __syncthreads();
  for (int s=0;s<3;s++){
    float2* dst = bufA + ((size_t)(b*30 + c*3 + s))*HW;
#pragma unroll
    for (int it=0; it<4; it++){
      int idx = it*256 + tid;
      int u = idx>>2, cp = idx&3;
      float2 e0 = lb[(s*8+2*cp  )*257 + swz(u)];
      float2 e1 = lb[(s*8+2*cp+1)*257 + swz(u)];
      *(float4*)(dst + u*256 + j0 + 2*cp) = make_float4(e0.x, e0.y, e1.x, e1.y);
    }
  }
}

// Fused CG p-update + S*p multiply + row-ifft. Block = (row r, b).
// If !first && !done: p = r + beta*p (beta = rs_acc/rs_old), written back.
// Last block: rs_old <- rs_acc, done check, zero pap & rs_acc (exact
// reference freeze semantics; this replaces the old k_upp + k_beta).
__global__ __launch_bounds__(256) void k_spfft(float2* __restrict__ p,
                                               const float2* __restrict__ rvec,
                                               const float* __restrict__ sr_,
                                               const float* __restrict__ si_,
                                               float2* __restrict__ bufA,
                                               Scal* sc, int first){
  __shared__ float2 lb[30*257];
  int tid = threadIdx.x, wave = tid>>6, lane = tid&63;
  int r = blockIdx.x, b = blockIdx.y;
  int k = tid;
  int done = sc->done;
  float beta = 0.f;
  if (!first) beta = (float)(sc->rs_acc / (sc->rs_old + 1e-20));
  float2 pv[3];
#pragma unroll
  for (int s=0;s<3;s++){
    size_t oi = (size_t)(b*3+s)*HW + (size_t)r*256 + k;
    if (!first && !done){
      float2 po = p[oi], rv = rvec[oi];
      float2 pn = make_float2(rv.x + beta*po.x, rv.y + beta*po.y);
      p[oi] = pn; pv[s] = pn;
    } else {
      pv[s] = p[oi];
    }
  }
  int sk = swz(k);
#pragma unroll
  for (int c=0;c<10;c++){
    size_t so = (size_t)(b*10+c)*HW + (size_t)r*256 + k;
    float2 sv = make_float2(sr_[so], si_[so]);
#pragma unroll
    for (int s=0;s<3;s++)
      lb[(c*3+s)*257 + sk] = cmul(sv, pv[s]);
  }
  __syncthreads();
  for (int pl=wave*2; pl<30; pl+=8){
    float2* lwA = &lb[pl*257];
    float2* lwB = &lb[(pl+1)*257];
    wave_fft256w_x2<1>(lwA, lwB, lane);
    float2* dA = bufA + (size_t)(b*30+pl)*HW + (size_t)r*256;
    float2* dB = bufA + (size_t)(b*30+pl+1)*HW + (size_t)r*256;
#pragma unroll
    for (int q=0;q<2;q++){
      int j = lane + 64*q;           // float4 index, 2 complex each
      float2 a0 = lwA[swz(2*j)], a1 = lwA[swz(2*j+1)];
      float2 b0 = lwB[swz(2*j)], b1 = lwB[swz(2*j+1)];
      *(float4*)(dA + 2*j) = make_float4(a0.x,a0.y,a1.x,a1.y);
      *(float4*)(dB + 2*j) = make_float4(b0.x,b0.y,b1.x,b1.y);
    }
  }
  if (tid==0){
    int total = (int)(gridDim.x*gridDim.y);
    int prev = atomicAdd(&sc->cnt, 1);
    if (prev == total-1){
      sc->cnt = 0;
      if (!first && !sc->done){
        sc->rs_old = sc->rs_acc;
        if (fabs(sc->rs_old) < 1e-10) sc->done = 1;
      }
      sc->pap_re = 0.0; sc->pap_im = 0.0; sc->rs_acc = 0.0;
    }
  }
}

// Fused row-fft + conj(S) combine + addend + dot. Block = (row r, b).
// SETUP=1: addend = lambda*D*MO; out=bvec; |out|^2 -> rs_acc
// SETUP=0: out = combined + LAM*p = Ap; conj(p).Ap -> pap
template<int SETUP>
__global__ __launch_bounds__(256) void k_rowcomb(const float2* __restrict__ bufA,
                                                 const float* __restrict__ sr_,
                                                 const float* __restrict__ si_,
                                                 const float* __restrict__ mor,
                                                 const float* __restrict__ moi,
                                                 const float2* __restrict__ pad,
                                                 float2* __restrict__ out,
                                                 Scal* sc){
  __shared__ float2 lb[30*257];
  __shared__ double sd[4], sd2[4];
  int tid = threadIdx.x, wave = tid>>6, lane = tid&63;
  int r = blockIdx.x, b = blockIdx.y;
  for (int pl=wave*2; pl<30; pl+=8){
    const float2* sA = bufA + (size_t)(b*30+pl)*HW + (size_t)r*256;
    const float2* sB = bufA + (size_t)(b*30+pl+1)*HW + (size_t)r*256;
    float2* lwA = &lb[pl*257];
    float2* lwB = &lb[(pl+1)*257];
#pragma unroll
    for (int q=0;q<2;q++){
      int j = lane + 64*q;
      float4 va = *(const float4*)(sA + 2*j);
      float4 vb = *(const float4*)(sB + 2*j);
      lwA[swz(2*j)] = make_float2(va.x,va.y); lwA[swz(2*j+1)] = make_float2(va.z,va.w);
      lwB[swz(2*j)] = make_float2(vb.x,vb.y); lwB[swz(2*j+1)] = make_float2(vb.z,vb.w);
    }
    wave_lds_sync();
    wave_fft256w_x2<-1>(lwA, lwB, lane);
  }
  __syncthreads();
  int k = tid, sk = swz(k);
  float2 a0 = make_float2(0,0), a1 = make_float2(0,0), a2 = make_float2(0,0);
#pragma unroll
  for (int c=0;c<10;c++){
    size_t so = (size_t)(b*10+c)*HW + (size_t)r*256 + k;
    float2 sv = make_float2(sr_[so], si_[so]);
    a0 = cadd(a0, cmulj(sv, lb[(c*3+0)*257 + sk]));
    a1 = cadd(a1, cmulj(sv, lb[(c*3+1)*257 + sk]));
    a2 = cadd(a2, cmulj(sv, lb[(c*3+2)*257 + sk]));
  }
  float2 accs[3] = {a0, a1, a2};
  double dre = 0.0, dim = 0.0;
#pragma unroll
  for (int s=0;s<3;s++){
    size_t oi = (size_t)(b*3+s)*HW + (size_t)r*256 + k;
    float2 acc = accs[s];
    if (SETUP){
      float sg = ((r ^ k) & 1) ? -1.f : 1.f;
      float sl = sg * LAM;
      acc.x += sl*mor[oi]; acc.y += sl*moi[oi];
      out[oi] = acc;
      dre += (double)acc.x*acc.x + (double)acc.y*acc.y;
    } else {
      float2 av = pad[oi];
      acc.x += LAM*av.x; acc.y += LAM*av.y;
      out[oi] = acc;
      dre += (double)av.x*acc.x + (double)av.y*acc.y;
      dim += (double)av.x*acc.y - (double)av.y*acc.x;
    }
  }
  for (int off=32; off>0; off>>=1){
    dre += __shfl_down(dre, off, 64);
    if (!SETUP) dim += __shfl_down(dim, off, 64);
  }
  if (lane==0){ sd[wave] = dre; sd2[wave] = dim; }
  __syncthreads();
  if (tid==0){
    double tre = sd[0]+sd[1]+sd[2]+sd[3];
    if (SETUP){
      atomicAdd(&sc->rs_acc, tre);
    } else {
      double tim = sd2[0]+sd2[1]+sd2[2]+sd2[3];
      atomicAdd(&sc->pap_re, tre);
      atomicAdd(&sc->pap_im, tim);
    }
  }
}

__global__ __launch_bounds__(256) void k_cginit(const float2* __restrict__ bvec,
                                                float2* __restrict__ z,
                                                float2* __restrict__ r,
                                                float2* __restrict__ p,
                                                Scal* sc){
  int i = blockIdx.x*256 + threadIdx.x;
  float2 bv = bvec[i];
  z[i] = make_float2(0.f,0.f);
  r[i] = bv; p[i] = bv;
  if (i==0){ sc->rs_old = sc->rs_acc; sc->pap_re=0.0; sc->pap_im=0.0; }
}

__global__ __launch_bounds__(256) void k_upzr(float2* __restrict__ z,
                                              float2* __restrict__ r,
                                              const float2* __restrict__ p,
                                              const float2* __restrict__ Ap,
                                              Scal* sc){
  __shared__ double sd[4];
  int tid = threadIdx.x;
  int i = blockIdx.x*256 + tid;
  int done = sc->done;
  double local = 0.0;
  if (!done){
    double dre = sc->pap_re + 1e-20, dim = sc->pap_im;
    double den = dre*dre + dim*dim;
    double rs = sc->rs_old;
    float2 alpha = make_float2((float)( rs*dre/den), (float)(-rs*dim/den));
    float2 pv = p[i], apv = Ap[i];
    float2 zv = cadd(z[i], cmul(alpha, pv));
    float2 rv = csub(r[i], cmul(alpha, apv));
    z[i] = zv; r[i] = rv;
    local = (double)rv.x*rv.x + (double)rv.y*rv.y;
  }
  for (int off=32; off>0; off>>=1) local += __shfl_down(local, off, 64);
  if ((tid&63)==0) sd[tid>>6] = local;
  __syncthreads();
  if (tid==0 && !done){
    atomicAdd(&sc->rs_acc, sd[0]+sd[1]+sd[2]+sd[3]);
  }
}

__global__ __launch_bounds__(256) void k_out(const float2* __restrict__ z,
                                             float* __restrict__ out){
  int i = blockIdx.x*256 + threadIdx.x;
  int pix = i & (HW-1);
  float sgn = (((pix>>8)^pix)&1) ? -1.f : 1.f;
  float2 zv = z[i];
  out[2*i]   = sgn*zv.x;
  out[2*i+1] = sgn*zv.y;
}

extern "C" void kernel_launch(void* const* d_in, const int* in_sizes, int n_in,
                              void* d_out, int out_size, void* d_ws, size_t ws_size,
                              hipStream_t stream){
  const float* kr   = (const float*)d_in[0];
  const float* ki   = (const float*)d_in[1];
  const float* mor  = (const float*)d_in[2];
  const float* moi  = (const float*)d_in[3];
  const float* sr   = (const float*)d_in[4];
  const float* si   = (const float*)d_in[5];
  const float* tbr  = (const float*)d_in[6];
  const float* tbi  = (const float*)d_in[7];
  const float* mask = (const float*)d_in[8];
  float* out = (float*)d_out;

  float2* ws   = (float2*)d_ws;
  float2* bufA = ws;                 // 60*HW float2
  float2* Wb   = ws + 3932160;       // 18*HW
  float2* bvec = ws + 5111808;       // 6*HW each below
  float2* z    = ws + 5505024;
  float2* r    = ws + 5898240;
  float2* p    = ws + 6291456;
  float2* Ap   = ws + 6684672;
  Scal*   sc   = (Scal*)(ws + 7077888);

  k_w<<<dim3(256,2),dim3(256),0,stream>>>(mask, tbr, tbi, Wb, sc);
  k_yhat<<<dim3(64,10,2),dim3(256),0,stream>>>(kr, ki, tbr, tbi, bufA);
  k_colpass<0><<<dim3(32,10,2),dim3(256),0,stream>>>(bufA, Wb);
  k_rowcomb<1><<<dim3(256,2),dim3(256),0,stream>>>(bufA, sr, si, mor, moi,
                                                   (const float2*)0, bvec, sc);
  k_cginit<<<dim3(1536),dim3(256),0,stream>>>(bvec, z, r, p, sc);
  for (int it=0; it<6; ++it){
    k_spfft<<<dim3(256,2),dim3(256),0,stream>>>(p, r, sr, si, bufA, sc, it==0 ? 1 : 0);
    k_colpass<1><<<dim3(32,10,2),dim3(256),0,stream>>>(bufA, Wb);
    k_rowcomb<0><<<dim3(256,2),dim3(256),0,stream>>>(bufA, sr, si,
                                                     (const float*)0,
                                                     (const float*)0,
                                                     p, Ap, sc);
    k_upzr<<<dim3(1536),dim3(256),0,stream>>>(z, r, p, Ap, sc);
  }
  k_out<<<dim3(1536),dim3(256),0,stream>>>(z, out);
}

// Round 6
// 750.308 us; speedup vs baseline: 1.3935x; 1.0146x over previous
//
// R6: radix-16 two-stage FFT (16 lanes/FFT, DFT-16 in registers; LDS traffic
// halved, syncs 4->3) + row-first setup (k_yhat deleted, fused k_yrow does
// L^H Y + row-fft; setup = yrow -> colpass<0> -> elementwise combine).
// Row kernels 512 thr (8w x 4 FFT slots = 30 planes in one round); colpass
// 384 thr (6w x 4 = 24 slots exact).
#include <hip/hip_runtime.h>
#include <math.h>

#define HW 65536
#define LAM 0.05f

struct Scal {
  double pap_re, pap_im, rs_acc, rs_old;
  int done, cnt;
};

__device__ __forceinline__ float2 cadd(float2 a, float2 b){ return make_float2(a.x+b.x, a.y+b.y); }
__device__ __forceinline__ float2 csub(float2 a, float2 b){ return make_float2(a.x-b.x, a.y-b.y); }
__device__ __forceinline__ float2 cmul(float2 a, float2 b){
  return make_float2(a.x*b.x - a.y*b.y, a.x*b.y + a.y*b.x);
}
__device__ __forceinline__ float2 cmulj(float2 a, float2 b){ // conj(a)*b
  return make_float2(a.x*b.x + a.y*b.y, a.x*b.y - a.y*b.x);
}
__device__ __forceinline__ int swz(int p){ return p ^ (p>>4); }

__device__ __forceinline__ void wave_lds_sync(){
  __builtin_amdgcn_wave_barrier();
  __asm__ __volatile__("s_waitcnt lgkmcnt(0)" ::: "memory");
  __builtin_amdgcn_wave_barrier();
}

// full DFT-4 (natural in/out), W4 = e^{S*2pi*i/4}
template<int S>
__device__ __forceinline__ void bfly4(float2 x0, float2 x1, float2 x2, float2 x3,
                                      float2& y0, float2& y1, float2& y2, float2& y3){
  float2 a  = cadd(x0,x2), bm = csub(x0,x2);
  float2 c  = cadd(x1,x3), d  = csub(x1,x3);
  float2 jd = make_float2(-(float)S*d.y, (float)S*d.x);
  y0 = cadd(a,c); y2 = csub(a,c); y1 = cadd(bm,jd); y3 = csub(bm,jd);
}

// in-register DFT-16, natural order in/out. W16 = e^{S*2pi*i/16}.
// A[k1+4k0] = DFT4_{n0}( W16^{n0 k1} * DFT4_{n1}(a[n0+4n1])[k1] )[k0]
template<int S>
__device__ __forceinline__ void dft16(float2* a){
  const float s_ = (float)S;
  const float2 W1 = make_float2( 0.92387953251f,  s_*0.38268343236f);
  const float2 W2 = make_float2( 0.70710678119f,  s_*0.70710678119f);
  const float2 W3 = make_float2( 0.38268343236f,  s_*0.92387953251f);
  const float2 W4_ = make_float2(0.f,              s_*1.f);
  const float2 W6 = make_float2(-0.70710678119f,  s_*0.70710678119f);
  const float2 W9 = make_float2(-0.92387953251f, -s_*0.38268343236f);
  float2 t[16];   // t[n0*4 + k1]
#pragma unroll
  for (int n0=0;n0<4;n0++){
    float2 y0,y1,y2,y3;
    bfly4<S>(a[n0], a[n0+4], a[n0+8], a[n0+12], y0,y1,y2,y3);
    if (n0==1){ y1=cmul(y1,W1); y2=cmul(y2,W2); y3=cmul(y3,W3); }
    if (n0==2){ y1=cmul(y1,W2); y2=cmul(y2,W4_); y3=cmul(y3,W6); }
    if (n0==3){ y1=cmul(y1,W3); y2=cmul(y2,W6); y3=cmul(y3,W9); }
    t[n0*4+0]=y0; t[n0*4+1]=y1; t[n0*4+2]=y2; t[n0*4+3]=y3;
  }
#pragma unroll
  for (int k1=0;k1<4;k1++){
    float2 y0,y1,y2,y3;
    bfly4<S>(t[0*4+k1], t[1*4+k1], t[2*4+k1], t[3*4+k1], y0,y1,y2,y3);
    a[k1+0]=y0; a[k1+4]=y1; a[k1+8]=y2; a[k1+12]=y3;
  }
}

// 256-pt FFT, two radix-16 stages, 16 lanes (l = lane&15) per FFT on a
// swizzled 256-float2 LDS slice. Natural order in/out. Caller must have
// synced staging writes. Ends with wave_lds_sync.
template<int S>
__device__ void fft256_r16(float2* buf, int l){
  float2 a[16];
#pragma unroll
  for (int j=0;j<16;j++) a[j] = buf[swz(l + 16*j)];   // lane-local set
  dft16<S>(a);
  float ang = (float)S * 6.2831853071795865f * (float)l * (1.f/256.f);
  float sn, cs; __sincosf(ang, &sn, &cs);
  float2 wstep = make_float2(cs, sn);
  float2 w = wstep;
#pragma unroll
  for (int k=1;k<16;k++){ a[k] = cmul(a[k], w); w = cmul(w, wstep); }
#pragma unroll
  for (int k=0;k<16;k++) buf[swz(16*k + l)] = a[k];   // same lane-local set
  wave_lds_sync();
#pragma unroll
  for (int j=0;j<16;j++) a[j] = buf[swz(16*l + j)];
  dft16<S>(a);
  wave_lds_sync();   // all reads drained before cross-lane scatter
#pragma unroll
  for (int k=0;k<16;k++) buf[swz(l + 16*k)] = a[k];
  wave_lds_sync();
}

// W[b][k=s*3+s'][v][u] = (1/65536) sum_t conj(L_ts) L_ts' mask[b,t,u,v]
__global__ __launch_bounds__(256) void k_w(const float* __restrict__ mask,
                                           const float* __restrict__ tbr,
                                           const float* __restrict__ tbi,
                                           float2* __restrict__ Wb,
                                           Scal* sc){
  if (blockIdx.x==0 && blockIdx.y==0 && threadIdx.x==0){
    sc->pap_re=0.0; sc->pap_im=0.0; sc->rs_acc=0.0; sc->rs_old=0.0;
    sc->done=0; sc->cnt=0;
  }
  __shared__ float2 wt[9][16][17];
  int tid = threadIdx.x;
  int bx = blockIdx.x;
  int b  = blockIdx.y;
  int u0 = (bx>>4)<<4, v0 = (bx&15)<<4;
  int u_l = tid>>4, v_l = tid&15;
  int pix = (u0+u_l)*256 + (v0+v_l);
  float d0=0,d1=0,d2=0, o01r=0,o01i=0, o02r=0,o02i=0, o12r=0,o12i=0;
#pragma unroll
  for (int t=0;t<12;t++){
    float m = mask[(size_t)(b*12+t)*HW + pix];
    int lb = (b*12+t)*3;
    float l0r = tbr[lb+0], l0i = tbi[lb+0];
    float l1r = tbr[lb+1], l1i = tbi[lb+1];
    float l2r = tbr[lb+2], l2i = tbi[lb+2];
    d0 += m*(l0r*l0r + l0i*l0i);
    d1 += m*(l1r*l1r + l1i*l1i);
    d2 += m*(l2r*l2r + l2i*l2i);
    o01r += m*(l0r*l1r + l0i*l1i); o01i += m*(l0r*l1i - l0i*l1r);
    o02r += m*(l0r*l2r + l0i*l2i); o02i += m*(l0r*l2i - l0i*l2r);
    o12r += m*(l1r*l2r + l1i*l2i); o12i += m*(l1r*l2i - l1i*l2r);
  }
  const float s = 1.0f/65536.0f;
  wt[0][u_l][v_l] = make_float2(d0*s, 0.f);
  wt[1][u_l][v_l] = make_float2(o01r*s,  o01i*s);
  wt[2][u_l][v_l] = make_float2(o02r*s,  o02i*s);
  wt[3][u_l][v_l] = make_float2(o01r*s, -o01i*s);
  wt[4][u_l][v_l] = make_float2(d1*s, 0.f);
  wt[5][u_l][v_l] = make_float2(o12r*s,  o12i*s);
  wt[6][u_l][v_l] = make_float2(o02r*s, -o02i*s);
  wt[7][u_l][v_l] = make_float2(o12r*s, -o12i*s);
  wt[8][u_l][v_l] = make_float2(d2*s, 0.f);
  __syncthreads();
  int u_l2 = tid&15, v_l2 = tid>>4;
#pragma unroll
  for (int k=0;k<9;k++){
    Wb[ ((size_t)(b*9+k)*256 + (v0+v_l2))*256 + (u0+u_l2) ] = wt[k][u_l2][v_l2];
  }
}

// Fused setup: bufA rows = row-fft( (1/256) * D * sum_t conj(L_ts) Y[b,t,c] )
// Block = (row r, b); halves handle coils 0-4 / 5-9; Y reads fully coalesced.
__global__ __launch_bounds__(512) void k_yrow(const float* __restrict__ kr,
                                              const float* __restrict__ ki,
                                              const float* __restrict__ tbr,
                                              const float* __restrict__ tbi,
                                              float2* __restrict__ bufA){
  __shared__ float2 lb[30*257];
  int tid = threadIdx.x;
  int wv = tid>>6, lane = tid&63, g = lane>>4, l = lane&15;
  int px = tid & 255, half = tid >> 8;
  int r = blockIdx.x, b = blockIdx.y;
  float sg = (((r ^ px) & 1) ? -1.f : 1.f) * (1.f/256.f);
  int sk = swz(px);
#pragma unroll
  for (int cc=0; cc<5; cc++){
    int c = half*5 + cc;
    float a0r=0,a0i=0,a1r=0,a1i=0,a2r=0,a2i=0;
#pragma unroll
    for (int t=0;t<12;t++){
      size_t off = ((size_t)((b*12+t)*10+c))*HW + (size_t)r*256 + px;
      float yr = kr[off], yi = ki[off];
      int lbi = (b*12+t)*3;
      float l0r = tbr[lbi+0], l0i = tbi[lbi+0];
      float l1r = tbr[lbi+1], l1i = tbi[lbi+1];
      float l2r = tbr[lbi+2], l2i = tbi[lbi+2];
      a0r += l0r*yr + l0i*yi;  a0i += l0r*yi - l0i*yr;
      a1r += l1r*yr + l1i*yi;  a1i += l1r*yi - l1i*yr;
      a2r += l2r*yr + l2i*yi;  a2i += l2r*yi - l2i*yr;
    }
    lb[(c*3+0)*257 + sk] = make_float2(a0r*sg, a0i*sg);
    lb[(c*3+1)*257 + sk] = make_float2(a1r*sg, a1i*sg);
    lb[(c*3+2)*257 + sk] = make_float2(a2r*sg, a2i*sg);
  }
  __syncthreads();
  int tau = 4*wv + g;
  if (tau < 30){
    float2* lw = &lb[tau*257];
    fft256_r16<-1>(lw, l);
    float2* dst = bufA + (size_t)(b*30+tau)*HW + (size_t)r*256;
#pragma unroll
    for (int j=0;j<8;j++){
      int e = 2*(16*j + l);
      float2 e0 = lw[swz(e)], e1 = lw[swz(e+1)];
      *(float4*)(dst + e) = make_float4(e0.x,e0.y,e1.x,e1.y);
    }
  }
}

// Column pass, in-place on bufA. 8 cols/block, 384 threads (24 FFT slots).
// MODE 0: col-fft (-1). MODE 1: col-ifft(+1) + W mix + col-fft(-1).
template<int MODE>
__global__ __launch_bounds__(384) void k_colpass(float2* __restrict__ bufA,
                                                 const float2* __restrict__ Wb){
  __shared__ float2 lb[24*257];
  int tid = threadIdx.x;
  int wv = tid>>6, lane = tid&63, g = lane>>4, l = lane&15;
  int j0 = blockIdx.x*8;
  int c = blockIdx.y, b = blockIdx.z;
#pragma unroll
  for (int it=0; it<8; it++){
    int idx = it*384 + tid;             // [0, 3072)
    int s = idx>>10, rem = idx&1023, u = rem>>2, cp = rem&3;
    const float2* src = bufA + (size_t)(b*30 + c*3 + s)*HW;
    float4 v = *(const float4*)(src + u*256 + j0 + 2*cp);
    lb[(s*8+2*cp  )*257 + swz(u)] = make_float2(v.x, v.y);
    lb[(s*8+2*cp+1)*257 + swz(u)] = make_float2(v.z, v.w);
  }
  __syncthreads();
  int tau = 4*wv + g;                   // [0,24)
  if (MODE==0){
    fft256_r16<-1>(&lb[tau*257], l);
  } else {
    fft256_r16<1>(&lb[tau*257], l);
    __syncthreads();
    const float2* Wp = Wb + (size_t)b*9*HW;
    for (int idx=tid; idx<2048; idx+=384){
      int u = idx&255, col = idx>>8;
      int su = swz(u);
      int v = j0 + col;
      float2 x0 = lb[(0*8+col)*257 + su];
      float2 x1 = lb[(1*8+col)*257 + su];
      float2 x2 = lb[(2*8+col)*257 + su];
      size_t wb = (size_t)v*256 + u;
      float2 y0 = cmul(Wp[(size_t)0*HW + wb], x0);
      y0 = cadd(y0, cmul(Wp[(size_t)1*HW + wb], x1));
      y0 = cadd(y0, cmul(Wp[(size_t)2*HW + wb], x2));
      float2 y1 = cmul(Wp[(size_t)3*HW + wb], x0);
      y1 = cadd(y1, cmul(Wp[(size_t)4*HW + wb], x1));
      y1 = cadd(y1, cmul(Wp[(size_t)5*HW + wb], x2));
      float2 y2 = cmul(Wp[(size_t)6*HW + wb], x0);
      y2 = cadd(y2, cmul(Wp[(size_t)7*HW + wb], x1));
      y2 = cadd(y2, cmul(Wp[(size_t)8*HW + wb], x2));
      lb[(0*8+col)*257 + su] = y0;
      lb[(1*8+col)*257 + su] = y1;
      lb[(2*8+col)*257 + su] = y2;
    }
    __syncthreads();
    fft256_r16<-1>(&lb[tau*257], l);
  }
  __syncthreads();
#pragma unroll
  for (int it=0; it<8; it++){
    int idx = it*384 + tid;
    int s = idx>>10, rem = idx&1023, u = rem>>2, cp = rem&3;
    float2* dst = bufA + (size_t)(b*30 + c*3 + s)*HW;
    float2 e0 = lb[(s*8+2*cp  )*257 + swz(u)];
    float2 e1 = lb[(s*8+2*cp+1)*257 + swz(u)];
    *(float4*)(dst + u*256 + j0 + 2*cp) = make_float4(e0.x, e0.y, e1.x, e1.y);
  }
}

// Setup combine: bvec = sum_c conj(S_c) bufA + lambda*D*MO; rs_acc += |bvec|^2
__global__ __launch_bounds__(256) void k_combine(const float2* __restrict__ bufA,
                                                 const float* __restrict__ sr_,
                                                 const float* __restrict__ si_,
                                                 const float* __restrict__ mor,
                                                 const float* __restrict__ moi,
                                                 float2* __restrict__ bvec,
                                                 Scal* sc){
  __shared__ double sd[4];
  int tid = threadIdx.x;
  int i = blockIdx.x*256 + tid;          // [0, 6*HW)
  int pix = i & (HW-1);
  int bs = i >> 16;                      // b*3+s
  int b = bs/3, s = bs - 3*b;
  float2 acc = make_float2(0.f, 0.f);
#pragma unroll
  for (int c=0;c<10;c++){
    float2 F  = bufA[(size_t)(b*30 + c*3 + s)*HW + pix];
    size_t so = (size_t)(b*10+c)*HW + pix;
    float2 sv = make_float2(sr_[so], si_[so]);
    acc = cadd(acc, cmulj(sv, F));
  }
  float sgl = (((pix>>8)^pix)&1 ? -1.f : 1.f) * LAM;
  acc.x += sgl*mor[i]; acc.y += sgl*moi[i];
  bvec[i] = acc;
  double dre = (double)acc.x*acc.x + (double)acc.y*acc.y;
  for (int off=32; off>0; off>>=1) dre += __shfl_down(dre, off, 64);
  if ((tid&63)==0) sd[tid>>6] = dre;
  __syncthreads();
  if (tid==0) atomicAdd(&sc->rs_acc, sd[0]+sd[1]+sd[2]+sd[3]);
}

// Fused CG p-update + S*p + row-ifft. Block = (row r, b), 512 threads.
// Threads <256 do the whole prologue (no cross-half p race). Last block
// advances the CG scalars (rs_old<-rs_acc, done check, zero pap/rs_acc).
__global__ __launch_bounds__(512) void k_spfft(float2* __restrict__ p,
                                               const float2* __restrict__ rvec,
                                               const float* __restrict__ sr_,
                                               const float* __restrict__ si_,
                                               float2* __restrict__ bufA,
                                               Scal* sc, int first){
  __shared__ float2 lb[30*257];
  int tid = threadIdx.x;
  int wv = tid>>6, lane = tid&63, g = lane>>4, l = lane&15;
  int r = blockIdx.x, b = blockIdx.y;
  if (tid < 256){
    int px = tid, sk = swz(px);
    int done = sc->done;
    float beta = first ? 0.f : (float)(sc->rs_acc / (sc->rs_old + 1e-20));
    float2 pv[3];
#pragma unroll
    for (int s=0;s<3;s++){
      size_t oi = (size_t)(b*3+s)*HW + (size_t)r*256 + px;
      if (!first && !done){
        float2 po = p[oi], rv = rvec[oi];
        float2 pn = make_float2(rv.x + beta*po.x, rv.y + beta*po.y);
        p[oi] = pn; pv[s] = pn;
      } else {
        pv[s] = p[oi];
      }
    }
#pragma unroll
    for (int c=0;c<10;c++){
      size_t so = (size_t)(b*10+c)*HW + (size_t)r*256 + px;
      float2 sv = make_float2(sr_[so], si_[so]);
      lb[(c*3+0)*257 + sk] = cmul(sv, pv[0]);
      lb[(c*3+1)*257 + sk] = cmul(sv, pv[1]);
      lb[(c*3+2)*257 + sk] = cmul(sv, pv[2]);
    }
  }
  __syncthreads();
  int tau = 4*wv + g;
  if (tau < 30){
    float2* lw = &lb[tau*257];
    fft256_r16<1>(lw, l);
    float2* dst = bufA + (size_t)(b*30+tau)*HW + (size_t)r*256;
#pragma unroll
    for (int j=0;j<8;j++){
      int e = 2*(16*j + l);
      float2 e0 = lw[swz(e)], e1 = lw[swz(e+1)];
      *(float4*)(dst + e) = make_float4(e0.x,e0.y,e1.x,e1.y);
    }
  }
  if (tid==0){
    int total = (int)(gridDim.x*gridDim.y);
    int prev = atomicAdd(&sc->cnt, 1);
    if (prev == total-1){
      sc->cnt = 0;
      if (!first && !sc->done){
        sc->rs_old = sc->rs_acc;
        if (fabs(sc->rs_old) < 1e-10) sc->done = 1;
      }
      sc->pap_re = 0.0; sc->pap_im = 0.0; sc->rs_acc = 0.0;
    }
  }
}

// Fused row-fft + conj(S) combine + LAM*p + conj(p).Ap reduction.
__global__ __launch_bounds__(512) void k_rowcomb(const float2* __restrict__ bufA,
                                                 const float* __restrict__ sr_,
                                                 const float* __restrict__ si_,
                                                 const float2* __restrict__ pvec,
                                                 float2* __restrict__ Ap,
                                                 Scal* sc){
  __shared__ float2 lb[30*257];
  __shared__ double sd[8], sd2[8];
  int tid = threadIdx.x;
  int wv = tid>>6, lane = tid&63, g = lane>>4, l = lane&15;
  int r = blockIdx.x, b = blockIdx.y;
  int tau = 4*wv + g;
  if (tau < 30){
    const float2* src = bufA + (size_t)(b*30+tau)*HW + (size_t)r*256;
    float2* lw = &lb[tau*257];
#pragma unroll
    for (int j=0;j<8;j++){
      int e = 2*(16*j + l);
      float4 v = *(const float4*)(src + e);
      lw[swz(e)]   = make_float2(v.x, v.y);
      lw[swz(e+1)] = make_float2(v.z, v.w);
    }
    wave_lds_sync();
    fft256_r16<-1>(lw, l);
  }
  __syncthreads();
  double dre = 0.0, dim = 0.0;
  if (tid < 256){
    int px = tid, sk = swz(px);
    float2 a0={0,0}, a1={0,0}, a2={0,0};
#pragma unroll
    for (int c=0;c<10;c++){
      size_t so = (size_t)(b*10+c)*HW + (size_t)r*256 + px;
      float2 sv = make_float2(sr_[so], si_[so]);
      a0 = cadd(a0, cmulj(sv, lb[(c*3+0)*257 + sk]));
      a1 = cadd(a1, cmulj(sv, lb[(c*3+1)*257 + sk]));
      a2 = cadd(a2, cmulj(sv, lb[(c*3+2)*257 + sk]));
    }
    float2 accs[3] = {a0,a1,a2};
#pragma unroll
    for (int s=0;s<3;s++){
      size_t oi = (size_t)(b*3+s)*HW + (size_t)r*256 + px;
      float2 acc = accs[s];
      float2 av = pvec[oi];
      acc.x += LAM*av.x; acc.y += LAM*av.y;
      Ap[oi] = acc;
      dre += (double)av.x*acc.x + (double)av.y*acc.y;
      dim += (double)av.x*acc.y - (double)av.y*acc.x;
    }
  }
  for (int off=32; off>0; off>>=1){
    dre += __shfl_down(dre, off, 64);
    dim += __shfl_down(dim, off, 64);
  }
  if (lane==0){ sd[wv]=dre; sd2[wv]=dim; }
  __syncthreads();
  if (tid==0){
    double tre=0.0, tim=0.0;
#pragma unroll
    for (int q=0;q<8;q++){ tre+=sd[q]; tim+=sd2[q]; }
    atomicAdd(&sc->pap_re, tre);
    atomicAdd(&sc->pap_im, tim);
  }
}

__global__ __launch_bounds__(256) void k_cginit(const float2* __restrict__ bvec,
                                                float2* __restrict__ z,
                                                float2* __restrict__ r,
                                                float2* __restrict__ p,
                                                Scal* sc){
  int i = blockIdx.x*256 + threadIdx.x;
  float2 bv = bvec[i];
  z[i] = make_float2(0.f,0.f);
  r[i] = bv; p[i] = bv;
  if (i==0){ sc->rs_old = sc->rs_acc; sc->pap_re=0.0; sc->pap_im=0.0; }
}

__global__ __launch_bounds__(256) void k_upzr(float2* __restrict__ z,
                                              float2* __restrict__ r,
                                              const float2* __restrict__ p,
                                              const float2* __restrict__ Ap,
                                              Scal* sc){
  __shared__ double sd[4];
  int tid = threadIdx.x;
  int i = blockIdx.x*256 + tid;
  int done = sc->done;
  double local = 0.0;
  if (!done){
    double dre = sc->pap_re + 1e-20, dim = sc->pap_im;
    double den = dre*dre + dim*dim;
    double rs = sc->rs_old;
    float2 alpha = make_float2((float)( rs*dre/den), (float)(-rs*dim/den));
    float2 pv = p[i], apv = Ap[i];
    float2 zv = cadd(z[i], cmul(alpha, pv));
    float2 rv = csub(r[i], cmul(alpha, apv));
    z[i] = zv; r[i] = rv;
    local = (double)rv.x*rv.x + (double)rv.y*rv.y;
  }
  for (int off=32; off>0; off>>=1) local += __shfl_down(local, off, 64);
  if ((tid&63)==0) sd[tid>>6] = local;
  __syncthreads();
  if (tid==0 && !done){
    atomicAdd(&sc->rs_acc, sd[0]+sd[1]+sd[2]+sd[3]);
  }
}

__global__ __launch_bounds__(256) void k_out(const float2* __restrict__ z,
                                             float* __restrict__ out){
  int i = blockIdx.x*256 + threadIdx.x;
  int pix = i & (HW-1);
  float sgn = (((pix>>8)^pix)&1) ? -1.f : 1.f;
  float2 zv = z[i];
  out[2*i]   = sgn*zv.x;
  out[2*i+1] = sgn*zv.y;
}

extern "C" void kernel_launch(void* const* d_in, const int* in_sizes, int n_in,
                              void* d_out, int out_size, void* d_ws, size_t ws_size,
                              hipStream_t stream){
  const float* kr   = (const float*)d_in[0];
  const float* ki   = (const float*)d_in[1];
  const float* mor  = (const float*)d_in[2];
  const float* moi  = (const float*)d_in[3];
  const float* sr   = (const float*)d_in[4];
  const float* si   = (const float*)d_in[5];
  const float* tbr  = (const float*)d_in[6];
  const float* tbi  = (const float*)d_in[7];
  const float* mask = (const float*)d_in[8];
  float* out = (float*)d_out;

  float2* ws   = (float2*)d_ws;
  float2* bufA = ws;                 // 60*HW float2
  float2* Wb   = ws + 3932160;       // 18*HW
  float2* bvec = ws + 5111808;       // 6*HW each below
  float2* z    = ws + 5505024;
  float2* r    = ws + 5898240;
  float2* p    = ws + 6291456;
  float2* Ap   = ws + 6684672;
  Scal*   sc   = (Scal*)(ws + 7077888);

  k_w<<<dim3(256,2),dim3(256),0,stream>>>(mask, tbr, tbi, Wb, sc);
  k_yrow<<<dim3(256,2),dim3(512),0,stream>>>(kr, ki, tbr, tbi, bufA);
  k_colpass<0><<<dim3(32,10,2),dim3(384),0,stream>>>(bufA, Wb);
  k_combine<<<dim3(1536),dim3(256),0,stream>>>(bufA, sr, si, mor, moi, bvec, sc);
  k_cginit<<<dim3(1536),dim3(256),0,stream>>>(bvec, z, r, p, sc);
  for (int it=0; it<6; ++it){
    k_spfft<<<dim3(256,2),dim3(512),0,stream>>>(p, r, sr, si, bufA, sc, it==0 ? 1 : 0);
    k_colpass<1><<<dim3(32,10,2),dim3(384),0,stream>>>(bufA, Wb);
    k_rowcomb<<<dim3(256,2),dim3(512),0,stream>>>(bufA, sr, si, p, Ap, sc);
    k_upzr<<<dim3(1536),dim3(256),0,stream>>>(z, r, p, Ap, sc);
  }
  k_out<<<dim3(1536),dim3(256),0,stream>>>(z, out);
}

// Round 7
// 726.634 us; speedup vs baseline: 1.4389x; 1.0326x over previous
//
// R7: CG-identity fusion + compressed W.
//  - upzr deleted: rowcomb accumulates pap, rq=<r,Ap>, qq=|Ap|^2; last block
//    computes alpha, rs_new = rs - 2Re(alpha*rq) + |alpha|^2 qq, beta, apply
//    flag (exact done-freeze). spfft prologue lazily applies z/r/p updates;
//    k_out applies the final z += alpha*p.
//  - W compressed to 9 floats/pixel (Hermitian 3x3): colpass W stream halved.
//  - cginit folded into combine (z=0, r=p=b, rs_old via atomic).
//  Dispatches 31 -> 23.
#include <hip/hip_runtime.h>
#include <math.h>

#define HW 65536
#define LAM 0.05f

struct Scal {
  double pap_re, pap_im, rq_re, rq_im, qq;
  double rs_old, al_re, al_im, beta;
  int done, apply, cnt, pad;
};

__device__ __forceinline__ float2 cadd(float2 a, float2 b){ return make_float2(a.x+b.x, a.y+b.y); }
__device__ __forceinline__ float2 csub(float2 a, float2 b){ return make_float2(a.x-b.x, a.y-b.y); }
__device__ __forceinline__ float2 cmul(float2 a, float2 b){
  return make_float2(a.x*b.x - a.y*b.y, a.x*b.y + a.y*b.x);
}
__device__ __forceinline__ float2 cmulj(float2 a, float2 b){ // conj(a)*b
  return make_float2(a.x*b.x + a.y*b.y, a.x*b.y - a.y*b.x);
}
__device__ __forceinline__ int swz(int p){ return p ^ (p>>4); }

__device__ __forceinline__ void wave_lds_sync(){
  __builtin_amdgcn_wave_barrier();
  __asm__ __volatile__("s_waitcnt lgkmcnt(0)" ::: "memory");
  __builtin_amdgcn_wave_barrier();
}

template<int S>
__device__ __forceinline__ void bfly4(float2 x0, float2 x1, float2 x2, float2 x3,
                                      float2& y0, float2& y1, float2& y2, float2& y3){
  float2 a  = cadd(x0,x2), bm = csub(x0,x2);
  float2 c  = cadd(x1,x3), d  = csub(x1,x3);
  float2 jd = make_float2(-(float)S*d.y, (float)S*d.x);
  y0 = cadd(a,c); y2 = csub(a,c); y1 = cadd(bm,jd); y3 = csub(bm,jd);
}

// in-register DFT-16, natural order in/out. W16 = e^{S*2pi*i/16}.
template<int S>
__device__ __forceinline__ void dft16(float2* a){
  const float s_ = (float)S;
  const float2 W1 = make_float2( 0.92387953251f,  s_*0.38268343236f);
  const float2 W2 = make_float2( 0.70710678119f,  s_*0.70710678119f);
  const float2 W3 = make_float2( 0.38268343236f,  s_*0.92387953251f);
  const float2 W4_ = make_float2(0.f,              s_*1.f);
  const float2 W6 = make_float2(-0.70710678119f,  s_*0.70710678119f);
  const float2 W9 = make_float2(-0.92387953251f, -s_*0.38268343236f);
  float2 t[16];
#pragma unroll
  for (int n0=0;n0<4;n0++){
    float2 y0,y1,y2,y3;
    bfly4<S>(a[n0], a[n0+4], a[n0+8], a[n0+12], y0,y1,y2,y3);
    if (n0==1){ y1=cmul(y1,W1); y2=cmul(y2,W2); y3=cmul(y3,W3); }
    if (n0==2){ y1=cmul(y1,W2); y2=cmul(y2,W4_); y3=cmul(y3,W6); }
    if (n0==3){ y1=cmul(y1,W3); y2=cmul(y2,W6); y3=cmul(y3,W9); }
    t[n0*4+0]=y0; t[n0*4+1]=y1; t[n0*4+2]=y2; t[n0*4+3]=y3;
  }
#pragma unroll
  for (int k1=0;k1<4;k1++){
    float2 y0,y1,y2,y3;
    bfly4<S>(t[0*4+k1], t[1*4+k1], t[2*4+k1], t[3*4+k1], y0,y1,y2,y3);
    a[k1+0]=y0; a[k1+4]=y1; a[k1+8]=y2; a[k1+12]=y3;
  }
}

// 256-pt FFT, two radix-16 stages, 16 lanes (l) per FFT, swizzled LDS slice.
template<int S>
__device__ void fft256_r16(float2* buf, int l){
  float2 a[16];
#pragma unroll
  for (int j=0;j<16;j++) a[j] = buf[swz(l + 16*j)];
  dft16<S>(a);
  float ang = (float)S * 6.2831853071795865f * (float)l * (1.f/256.f);
  float sn, cs; __sincosf(ang, &sn, &cs);
  float2 wstep = make_float2(cs, sn);
  float2 w = wstep;
#pragma unroll
  for (int k=1;k<16;k++){ a[k] = cmul(a[k], w); w = cmul(w, wstep); }
#pragma unroll
  for (int k=0;k<16;k++) buf[swz(16*k + l)] = a[k];
  wave_lds_sync();
#pragma unroll
  for (int j=0;j<16;j++) a[j] = buf[swz(16*l + j)];
  dft16<S>(a);
  wave_lds_sync();
#pragma unroll
  for (int k=0;k<16;k++) buf[swz(l + 16*k)] = a[k];
  wave_lds_sync();
}

// Compressed W: 9 float planes [b][f][v][u], f = {d0,d1,d2,o01r,o01i,o02r,
// o02i,o12r,o12i}, folded 1/65536 norm. Also inits Scal (block 0).
__global__ __launch_bounds__(256) void k_w(const float* __restrict__ mask,
                                           const float* __restrict__ tbr,
                                           const float* __restrict__ tbi,
                                           float* __restrict__ Wf,
                                           Scal* sc){
  if (blockIdx.x==0 && blockIdx.y==0 && threadIdx.x==0){
    sc->pap_re=0.0; sc->pap_im=0.0; sc->rq_re=0.0; sc->rq_im=0.0; sc->qq=0.0;
    sc->rs_old=0.0; sc->al_re=0.0; sc->al_im=0.0; sc->beta=0.0;
    sc->done=0; sc->apply=0; sc->cnt=0;
  }
  __shared__ float wtf[9][16][17];
  int tid = threadIdx.x;
  int bx = blockIdx.x;
  int b  = blockIdx.y;
  int u0 = (bx>>4)<<4, v0 = (bx&15)<<4;
  int u_l = tid>>4, v_l = tid&15;
  int pix = (u0+u_l)*256 + (v0+v_l);
  float d0=0,d1=0,d2=0, o01r=0,o01i=0, o02r=0,o02i=0, o12r=0,o12i=0;
#pragma unroll
  for (int t=0;t<12;t++){
    float m = mask[(size_t)(b*12+t)*HW + pix];
    int lb = (b*12+t)*3;
    float l0r = tbr[lb+0], l0i = tbi[lb+0];
    float l1r = tbr[lb+1], l1i = tbi[lb+1];
    float l2r = tbr[lb+2], l2i = tbi[lb+2];
    d0 += m*(l0r*l0r + l0i*l0i);
    d1 += m*(l1r*l1r + l1i*l1i);
    d2 += m*(l2r*l2r + l2i*l2i);
    o01r += m*(l0r*l1r + l0i*l1i); o01i += m*(l0r*l1i - l0i*l1r);
    o02r += m*(l0r*l2r + l0i*l2i); o02i += m*(l0r*l2i - l0i*l2r);
    o12r += m*(l1r*l2r + l1i*l2i); o12i += m*(l1r*l2i - l1i*l2r);
  }
  const float s = 1.0f/65536.0f;
  wtf[0][u_l][v_l] = d0*s;   wtf[1][u_l][v_l] = d1*s;   wtf[2][u_l][v_l] = d2*s;
  wtf[3][u_l][v_l] = o01r*s; wtf[4][u_l][v_l] = o01i*s;
  wtf[5][u_l][v_l] = o02r*s; wtf[6][u_l][v_l] = o02i*s;
  wtf[7][u_l][v_l] = o12r*s; wtf[8][u_l][v_l] = o12i*s;
  __syncthreads();
  int u_l2 = tid&15, v_l2 = tid>>4;
#pragma unroll
  for (int f=0;f<9;f++){
    Wf[ ((size_t)(b*9+f)*256 + (v0+v_l2))*256 + (u0+u_l2) ] = wtf[f][u_l2][v_l2];
  }
}

// Fused setup: bufA rows = row-fft( (1/256) * D * sum_t conj(L_ts) Y[b,t,c] )
__global__ __launch_bounds__(512) void k_yrow(const float* __restrict__ kr,
                                              const float* __restrict__ ki,
                                              const float* __restrict__ tbr,
                                              const float* __restrict__ tbi,
                                              float2* __restrict__ bufA){
  __shared__ float2 lb[30*257];
  int tid = threadIdx.x;
  int wv = tid>>6, lane = tid&63, g = lane>>4, l = lane&15;
  int px = tid & 255, half = tid >> 8;
  int r = blockIdx.x, b = blockIdx.y;
  float sg = (((r ^ px) & 1) ? -1.f : 1.f) * (1.f/256.f);
  int sk = swz(px);
#pragma unroll
  for (int cc=0; cc<5; cc++){
    int c = half*5 + cc;
    float a0r=0,a0i=0,a1r=0,a1i=0,a2r=0,a2i=0;
#pragma unroll
    for (int t=0;t<12;t++){
      size_t off = ((size_t)((b*12+t)*10+c))*HW + (size_t)r*256 + px;
      float yr = kr[off], yi = ki[off];
      int lbi = (b*12+t)*3;
      float l0r = tbr[lbi+0], l0i = tbi[lbi+0];
      float l1r = tbr[lbi+1], l1i = tbi[lbi+1];
      float l2r = tbr[lbi+2], l2i = tbi[lbi+2];
      a0r += l0r*yr + l0i*yi;  a0i += l0r*yi - l0i*yr;
      a1r += l1r*yr + l1i*yi;  a1i += l1r*yi - l1i*yr;
      a2r += l2r*yr + l2i*yi;  a2i += l2r*yi - l2i*yr;
    }
    lb[(c*3+0)*257 + sk] = make_float2(a0r*sg, a0i*sg);
    lb[(c*3+1)*257 + sk] = make_float2(a1r*sg, a1i*sg);
    lb[(c*3+2)*257 + sk] = make_float2(a2r*sg, a2i*sg);
  }
  __syncthreads();
  int tau = 4*wv + g;
  if (tau < 30){
    float2* lw = &lb[tau*257];
    fft256_r16<-1>(lw, l);
    float2* dst = bufA + (size_t)(b*30+tau)*HW + (size_t)r*256;
#pragma unroll
    for (int j=0;j<8;j++){
      int e = 2*(16*j + l);
      float2 e0 = lw[swz(e)], e1 = lw[swz(e+1)];
      *(float4*)(dst + e) = make_float4(e0.x,e0.y,e1.x,e1.y);
    }
  }
}

// Column pass, in-place. 8 cols/block, 384 threads (24 FFT slots).
// MODE 0: col-fft (-1). MODE 1: col-ifft(+1) + Hermitian W mix + col-fft(-1).
template<int MODE>
__global__ __launch_bounds__(384) void k_colpass(float2* __restrict__ bufA,
                                                 const float* __restrict__ Wf){
  __shared__ float2 lb[24*257];
  int tid = threadIdx.x;
  int wv = tid>>6, lane = tid&63, g = lane>>4, l = lane&15;
  int j0 = blockIdx.x*8;
  int c = blockIdx.y, b = blockIdx.z;
#pragma unroll
  for (int it=0; it<8; it++){
    int idx = it*384 + tid;
    int s = idx>>10, rem = idx&1023, u = rem>>2, cp = rem&3;
    const float2* src = bufA + (size_t)(b*30 + c*3 + s)*HW;
    float4 v = *(const float4*)(src + u*256 + j0 + 2*cp);
    lb[(s*8+2*cp  )*257 + swz(u)] = make_float2(v.x, v.y);
    lb[(s*8+2*cp+1)*257 + swz(u)] = make_float2(v.z, v.w);
  }
  __syncthreads();
  int tau = 4*wv + g;
  if (MODE==0){
    fft256_r16<-1>(&lb[tau*257], l);
  } else {
    fft256_r16<1>(&lb[tau*257], l);
    __syncthreads();
    const float* W0 = Wf + (size_t)b*9*HW;
    for (int idx=tid; idx<2048; idx+=384){
      int u = idx&255, col = idx>>8;
      int su = swz(u);
      int v = j0 + col;
      float2 x0 = lb[(0*8+col)*257 + su];
      float2 x1 = lb[(1*8+col)*257 + su];
      float2 x2 = lb[(2*8+col)*257 + su];
      size_t wb = (size_t)v*256 + u;
      float d0  = W0[(size_t)0*HW + wb];
      float d1  = W0[(size_t)1*HW + wb];
      float d2  = W0[(size_t)2*HW + wb];
      float o01r= W0[(size_t)3*HW + wb], o01i = W0[(size_t)4*HW + wb];
      float o02r= W0[(size_t)5*HW + wb], o02i = W0[(size_t)6*HW + wb];
      float o12r= W0[(size_t)7*HW + wb], o12i = W0[(size_t)8*HW + wb];
      float2 y0, y1, y2;
      y0.x = d0*x0.x + o01r*x1.x - o01i*x1.y + o02r*x2.x - o02i*x2.y;
      y0.y = d0*x0.y + o01r*x1.y + o01i*x1.x + o02r*x2.y + o02i*x2.x;
      y1.x = o01r*x0.x + o01i*x0.y + d1*x1.x + o12r*x2.x - o12i*x2.y;
      y1.y = o01r*x0.y - o01i*x0.x + d1*x1.y + o12r*x2.y + o12i*x2.x;
      y2.x = o02r*x0.x + o02i*x0.y + o12r*x1.x + o12i*x1.y + d2*x2.x;
      y2.y = o02r*x0.y - o02i*x0.x + o12r*x1.y - o12i*x1.x + d2*x2.y;
      lb[(0*8+col)*257 + su] = y0;
      lb[(1*8+col)*257 + su] = y1;
      lb[(2*8+col)*257 + su] = y2;
    }
    __syncthreads();
    fft256_r16<-1>(&lb[tau*257], l);
  }
  __syncthreads();
#pragma unroll
  for (int it=0; it<8; it++){
    int idx = it*384 + tid;
    int s = idx>>10, rem = idx&1023, u = rem>>2, cp = rem&3;
    float2* dst = bufA + (size_t)(b*30 + c*3 + s)*HW;
    float2 e0 = lb[(s*8+2*cp  )*257 + swz(u)];
    float2 e1 = lb[(s*8+2*cp+1)*257 + swz(u)];
    *(float4*)(dst + u*256 + j0 + 2*cp) = make_float4(e0.x, e0.y, e1.x, e1.y);
  }
}

// Setup combine: b = sum_c conj(S_c) bufA + lambda*D*MO; z=0, r=p=b;
// rs_old += |b|^2 (atomic).
__global__ __launch_bounds__(256) void k_combine(const float2* __restrict__ bufA,
                                                 const float* __restrict__ sr_,
                                                 const float* __restrict__ si_,
                                                 const float* __restrict__ mor,
                                                 const float* __restrict__ moi,
                                                 float2* __restrict__ z,
                                                 float2* __restrict__ r,
                                                 float2* __restrict__ p,
                                                 Scal* sc){
  __shared__ double sd[4];
  int tid = threadIdx.x;
  int i = blockIdx.x*256 + tid;          // [0, 6*HW)
  int pix = i & (HW-1);
  int bs = i >> 16;
  int b = bs/3, s = bs - 3*b;
  float2 acc = make_float2(0.f, 0.f);
#pragma unroll
  for (int c=0;c<10;c++){
    float2 F  = bufA[(size_t)(b*30 + c*3 + s)*HW + pix];
    size_t so = (size_t)(b*10+c)*HW + pix;
    float2 sv = make_float2(sr_[so], si_[so]);
    acc = cadd(acc, cmulj(sv, F));
  }
  float sgl = (((pix>>8)^pix)&1 ? -1.f : 1.f) * LAM;
  acc.x += sgl*mor[i]; acc.y += sgl*moi[i];
  z[i] = make_float2(0.f,0.f);
  r[i] = acc; p[i] = acc;
  double dre = (double)acc.x*acc.x + (double)acc.y*acc.y;
  for (int off=32; off>0; off>>=1) dre += __shfl_down(dre, off, 64);
  if ((tid&63)==0) sd[tid>>6] = dre;
  __syncthreads();
  if (tid==0) atomicAdd(&sc->rs_old, sd[0]+sd[1]+sd[2]+sd[3]);
}

// Fused lazy CG update (z += a*p, r -= a*Ap, p = r + beta*p, when apply)
// + S*p + row-ifft. Block = (row r, b), 512 threads.
__global__ __launch_bounds__(512) void k_spfft(float2* __restrict__ p,
                                               float2* __restrict__ rvec,
                                               float2* __restrict__ z,
                                               const float2* __restrict__ Ap,
                                               const float* __restrict__ sr_,
                                               const float* __restrict__ si_,
                                               float2* __restrict__ bufA,
                                               Scal* sc){
  __shared__ float2 lb[30*257];
  int tid = threadIdx.x;
  int wv = tid>>6, lane = tid&63, g = lane>>4, l = lane&15;
  int r = blockIdx.x, b = blockIdx.y;
  if (tid < 256){
    int px = tid, sk = swz(px);
    int ap = sc->apply;
    float2 alpha = make_float2((float)sc->al_re, (float)sc->al_im);
    float beta = (float)sc->beta;
    float2 pv[3];
#pragma unroll
    for (int s=0;s<3;s++){
      size_t oi = (size_t)(b*3+s)*HW + (size_t)r*256 + px;
      float2 pvv = p[oi];
      if (ap){
        float2 zv = z[oi], rv = rvec[oi], apv = Ap[oi];
        zv = cadd(zv, cmul(alpha, pvv));
        rv = csub(rv, cmul(alpha, apv));
        float2 pn = make_float2(rv.x + beta*pvv.x, rv.y + beta*pvv.y);
        z[oi] = zv; rvec[oi] = rv; p[oi] = pn;
        pvv = pn;
      }
      pv[s] = pvv;
    }
#pragma unroll
    for (int c=0;c<10;c++){
      size_t so = (size_t)(b*10+c)*HW + (size_t)r*256 + px;
      float2 sv = make_float2(sr_[so], si_[so]);
      lb[(c*3+0)*257 + sk] = cmul(sv, pv[0]);
      lb[(c*3+1)*257 + sk] = cmul(sv, pv[1]);
      lb[(c*3+2)*257 + sk] = cmul(sv, pv[2]);
    }
  }
  __syncthreads();
  int tau = 4*wv + g;
  if (tau < 30){
    float2* lw = &lb[tau*257];
    fft256_r16<1>(lw, l);
    float2* dst = bufA + (size_t)(b*30+tau)*HW + (size_t)r*256;
#pragma unroll
    for (int j=0;j<8;j++){
      int e = 2*(16*j + l);
      float2 e0 = lw[swz(e)], e1 = lw[swz(e+1)];
      *(float4*)(dst + e) = make_float4(e0.x,e0.y,e1.x,e1.y);
    }
  }
}

// Fused row-fft + conj(S) combine + LAM*p + dot accumulation
// (pap=<p,Ap>, rq=<r,Ap>, qq=<Ap,Ap>); last block advances CG scalars.
__global__ __launch_bounds__(512) void k_rowcomb(const float2* __restrict__ bufA,
                                                 const float* __restrict__ sr_,
                                                 const float* __restrict__ si_,
                                                 const float2* __restrict__ pvec,
                                                 const float2* __restrict__ rvec,
                                                 float2* __restrict__ Ap,
                                                 Scal* sc){
  __shared__ float2 lb[30*257];
  __shared__ double sd[5][8];
  int tid = threadIdx.x;
  int wv = tid>>6, lane = tid&63, g = lane>>4, l = lane&15;
  int r = blockIdx.x, b = blockIdx.y;
  int tau = 4*wv + g;
  if (tau < 30){
    const float2* src = bufA + (size_t)(b*30+tau)*HW + (size_t)r*256;
    float2* lw = &lb[tau*257];
#pragma unroll
    for (int j=0;j<8;j++){
      int e = 2*(16*j + l);
      float4 v = *(const float4*)(src + e);
      lw[swz(e)]   = make_float2(v.x, v.y);
      lw[swz(e+1)] = make_float2(v.z, v.w);
    }
    wave_lds_sync();
    fft256_r16<-1>(lw, l);
  }
  __syncthreads();
  double d0=0.0, d1=0.0, d2=0.0, d3=0.0, d4=0.0;
  if (tid < 256){
    int px = tid, sk = swz(px);
    float2 a0={0,0}, a1={0,0}, a2={0,0};
#pragma unroll
    for (int c=0;c<10;c++){
      size_t so = (size_t)(b*10+c)*HW + (size_t)r*256 + px;
      float2 sv = make_float2(sr_[so], si_[so]);
      a0 = cadd(a0, cmulj(sv, lb[(c*3+0)*257 + sk]));
      a1 = cadd(a1, cmulj(sv, lb[(c*3+1)*257 + sk]));
      a2 = cadd(a2, cmulj(sv, lb[(c*3+2)*257 + sk]));
    }
    float2 accs[3] = {a0,a1,a2};
#pragma unroll
    for (int s=0;s<3;s++){
      size_t oi = (size_t)(b*3+s)*HW + (size_t)r*256 + px;
      float2 acc = accs[s];
      float2 av = pvec[oi];
      float2 rv = rvec[oi];
      acc.x += LAM*av.x; acc.y += LAM*av.y;
      Ap[oi] = acc;
      d0 += (double)av.x*acc.x + (double)av.y*acc.y;   // pap
      d1 += (double)av.x*acc.y - (double)av.y*acc.x;
      d2 += (double)rv.x*acc.x + (double)rv.y*acc.y;   // rq
      d3 += (double)rv.x*acc.y - (double)rv.y*acc.x;
      d4 += (double)acc.x*acc.x + (double)acc.y*acc.y; // qq
    }
  }
  for (int off=32; off>0; off>>=1){
    d0 += __shfl_down(d0, off, 64);
    d1 += __shfl_down(d1, off, 64);
    d2 += __shfl_down(d2, off, 64);
    d3 += __shfl_down(d3, off, 64);
    d4 += __shfl_down(d4, off, 64);
  }
  if (lane==0){ sd[0][wv]=d0; sd[1][wv]=d1; sd[2][wv]=d2; sd[3][wv]=d3; sd[4][wv]=d4; }
  __syncthreads();
  if (tid==0){
    double t0=0,t1=0,t2=0,t3=0,t4=0;
#pragma unroll
    for (int q=0;q<8;q++){ t0+=sd[0][q]; t1+=sd[1][q]; t2+=sd[2][q]; t3+=sd[3][q]; t4+=sd[4][q]; }
    atomicAdd(&sc->pap_re, t0); atomicAdd(&sc->pap_im, t1);
    atomicAdd(&sc->rq_re,  t2); atomicAdd(&sc->rq_im,  t3);
    atomicAdd(&sc->qq,     t4);
    int total = (int)(gridDim.x*gridDim.y);
    int prev = atomicAdd(&sc->cnt, 1);
    if (prev == total-1){
      sc->cnt = 0;
      if (!sc->done){
        double pr = sc->pap_re + 1e-20, pi = sc->pap_im;
        double den = pr*pr + pi*pi;
        double rs = sc->rs_old;
        double alr =  rs*pr/den, ali = -rs*pi/den;
        double rs_new = rs - 2.0*(alr*sc->rq_re - ali*sc->rq_im)
                           + (alr*alr + ali*ali)*sc->qq;
        sc->al_re = alr; sc->al_im = ali;
        sc->beta = rs_new/(rs + 1e-20);
        sc->rs_old = rs_new;
        sc->apply = 1;
        if (fabs(rs_new) < 1e-10) sc->done = 1;
      } else {
        sc->apply = 0;
      }
      sc->pap_re=0.0; sc->pap_im=0.0; sc->rq_re=0.0; sc->rq_im=0.0; sc->qq=0.0;
    }
  }
}

// Output: apply pending z += alpha*p, un-tilde (D), interleave re/im.
__global__ __launch_bounds__(256) void k_out(const float2* __restrict__ z,
                                             const float2* __restrict__ p,
                                             const Scal* sc,
                                             float* __restrict__ out){
  int i = blockIdx.x*256 + threadIdx.x;
  int pix = i & (HW-1);
  float sgn = (((pix>>8)^pix)&1) ? -1.f : 1.f;
  float2 zv = z[i];
  if (sc->apply){
    float2 alpha = make_float2((float)sc->al_re, (float)sc->al_im);
    zv = cadd(zv, cmul(alpha, p[i]));
  }
  out[2*i]   = sgn*zv.x;
  out[2*i+1] = sgn*zv.y;
}

extern "C" void kernel_launch(void* const* d_in, const int* in_sizes, int n_in,
                              void* d_out, int out_size, void* d_ws, size_t ws_size,
                              hipStream_t stream){
  const float* kr   = (const float*)d_in[0];
  const float* ki   = (const float*)d_in[1];
  const float* mor  = (const float*)d_in[2];
  const float* moi  = (const float*)d_in[3];
  const float* sr   = (const float*)d_in[4];
  const float* si   = (const float*)d_in[5];
  const float* tbr  = (const float*)d_in[6];
  const float* tbi  = (const float*)d_in[7];
  const float* mask = (const float*)d_in[8];
  float* out = (float*)d_out;

  float2* ws   = (float2*)d_ws;
  float2* bufA = ws;                       // 60*HW float2
  float*  Wf   = (float*)(ws + 3932160);   // 18*HW floats (9*HW float2 slots)
  float2* z    = ws + 4521984;             // 6*HW each
  float2* r    = ws + 4915200;
  float2* p    = ws + 5308416;
  float2* Ap   = ws + 5701632;
  Scal*   sc   = (Scal*)(ws + 6094848);

  k_w<<<dim3(256,2),dim3(256),0,stream>>>(mask, tbr, tbi, Wf, sc);
  k_yrow<<<dim3(256,2),dim3(512),0,stream>>>(kr, ki, tbr, tbi, bufA);
  k_colpass<0><<<dim3(32,10,2),dim3(384),0,stream>>>(bufA, Wf);
  k_combine<<<dim3(1536),dim3(256),0,stream>>>(bufA, sr, si, mor, moi,
                                               z, r, p, sc);
  for (int it=0; it<6; ++it){
    k_spfft<<<dim3(256,2),dim3(512),0,stream>>>(p, r, z, Ap, sr, si, bufA, sc);
    k_colpass<1><<<dim3(32,10,2),dim3(384),0,stream>>>(bufA, Wf);
    k_rowcomb<<<dim3(256,2),dim3(512),0,stream>>>(bufA, sr, si, p, r, Ap, sc);
  }
  k_out<<<dim3(1536),dim3(256),0,stream>>>(z, p, sc, out);
}